// Round 9
// baseline (1060.501 us; speedup 1.0000x reference)
//
#include <hip/hip_runtime.h>
#include <math.h>

#define BB 2
#define LL 1024
#define CCH 512
#define HH 8
#define LN_EPSF 1e-5f
#define NBLK 1024

typedef short s16x8 __attribute__((ext_vector_type(8)));
typedef float fx4 __attribute__((ext_vector_type(4)));

__device__ __forceinline__ unsigned short f2bf(float f) {
  unsigned u = __float_as_uint(f);
  unsigned r = (u + 0x7FFFu + ((u >> 16) & 1u)) >> 16;
  return (unsigned short)r;
}
__device__ __forceinline__ float bf2f(unsigned short h) {
  return __uint_as_float(((unsigned)h) << 16);
}
__device__ __forceinline__ s16x8 ldfrag(const unsigned short* p) {
  int4 t = *(const int4*)p;
  return *(s16x8*)&t;
}

// ---- DPP row_ror reductions over 16-lane rows ----
template <int CTRL>
__device__ __forceinline__ float dpp_mov(float x) {
  return __int_as_float(
      __builtin_amdgcn_update_dpp(0, __float_as_int(x), CTRL, 0xF, 0xF, true));
}
__device__ __forceinline__ float red16_sum(float v) {
  v += dpp_mov<0x121>(v);
  v += dpp_mov<0x122>(v);
  v += dpp_mov<0x124>(v);
  v += dpp_mov<0x128>(v);
  return v;
}
__device__ __forceinline__ float red16_max(float v) {
  v = fmaxf(v, dpp_mov<0x121>(v));
  v = fmaxf(v, dpp_mov<0x122>(v));
  v = fmaxf(v, dpp_mov<0x124>(v));
  v = fmaxf(v, dpp_mov<0x128>(v));
  return v;
}
__device__ __forceinline__ float wave_sum(float v) {
  v = red16_sum(v);
  v += __shfl_xor(v, 16);
  v += __shfl_xor(v, 32);
  return v;
}

// ---- shared memory union across phases ----
struct SPrep { unsigned short lh[64][68]; float red[8]; };
struct SProj { unsigned short vt[64][72]; };
struct SIpa {
  unsigned short pb[4][16][32];
  float obuf[4][16][64];
  float mred[4][16], lred[4][16];
  float qsl[4][16];
};
union SAll { SPrep prep; SProj proj; SIpa ipa; };

// ---- device-scope grid barrier (all NBLK blocks co-resident by construction) ----
__device__ __forceinline__ void grid_barrier(int* bar) {
  __syncthreads();
  if (threadIdx.x == 0) {
    __threadfence();  // release prior writes device-wide
    int gen = __hip_atomic_load(&bar[1], __ATOMIC_RELAXED, __HIP_MEMORY_SCOPE_AGENT);
    int old = __hip_atomic_fetch_add(&bar[0], 1, __ATOMIC_ACQ_REL, __HIP_MEMORY_SCOPE_AGENT);
    if (old == NBLK - 1) {
      __hip_atomic_store(&bar[0], 0, __ATOMIC_RELAXED, __HIP_MEMORY_SCOPE_AGENT);
      __hip_atomic_fetch_add(&bar[1], 1, __ATOMIC_RELEASE, __HIP_MEMORY_SCOPE_AGENT);
    } else {
      while (__hip_atomic_load(&bar[1], __ATOMIC_ACQUIRE, __HIP_MEMORY_SCOPE_AGENT) == gen)
        __builtin_amdgcn_s_sleep(8);
    }
    __threadfence();  // acquire others' writes
  }
  __syncthreads();
}

// ---------------- P0a: LayerNorm (vb<2048) / weight pack (vb 2048..2335) ----------------
__device__ void prep_body(int vb, const float* __restrict__ f,
                          const float* __restrict__ g, const float* __restrict__ bta,
                          unsigned short* __restrict__ xh, unsigned short* __restrict__ xl,
                          const float* __restrict__ wq, const float* __restrict__ wk,
                          const float* __restrict__ wv, const float* __restrict__ wo,
                          const float* __restrict__ wqp, const float* __restrict__ wkp,
                          unsigned short* __restrict__ wt_h, SAll& sm) {
  const int tid = threadIdx.x;
  if (vb < 2048) {  // LayerNorm
    const int row = vb;
    const int wave = tid >> 6, lane = tid & 63;
    float* red = sm.prep.red;
    const float* fr = f + (size_t)row * CCH;
    float2 v = *(const float2*)&fr[tid * 2];
    float s = wave_sum(v.x + v.y);
    if (lane == 0) red[wave] = s;
    __syncthreads();
    float mu = (red[0] + red[1] + red[2] + red[3]) * (1.0f / CCH);
    float dx = v.x - mu, dy = v.y - mu;
    float sq = wave_sum(dx * dx + dy * dy);
    if (lane == 0) red[4 + wave] = sq;
    __syncthreads();
    float var = (red[4] + red[5] + red[6] + red[7]) * (1.0f / CCH);
    float inv = 1.0f / sqrtf(var + LN_EPSF);
    float2 gg = *(const float2*)&g[tid * 2];
    float2 bb = *(const float2*)&bta[tid * 2];
    float ox = dx * inv * gg.x + bb.x;
    float oy = dy * inv * gg.y + bb.y;
    unsigned short h0 = f2bf(ox), h1 = f2bf(oy);
    ushort2 hv; hv.x = h0; hv.y = h1;
    ushort2 lv; lv.x = f2bf(ox - bf2f(h0)); lv.y = f2bf(oy - bf2f(h1));
    *(ushort2*)&xh[(size_t)row * CCH + tid * 2] = hv;
    *(ushort2*)&xl[(size_t)row * CCH + tid * 2] = lv;
    __syncthreads();  // protect red vs next virtual iteration
  } else {  // weight pack
    const int bx = vb - 2048;
    const float* W;
    int Ncols, rowbase, kt, nt;
    if (bx < 256) {
      int mat = bx >> 6, t = bx & 63;
      kt = t >> 3; nt = t & 7; Ncols = 512;
      if (mat == 0) { W = wq; rowbase = 0; }
      else if (mat == 1) { W = wk; rowbase = 512; }
      else if (mat == 2) { W = wv; rowbase = 1024; }
      else { W = wo; rowbase = 1536; }
    } else {
      int r = bx - 256; int mat = r >> 4; int t = r & 15;
      kt = t >> 1; nt = t & 1; Ncols = 96;
      if (mat == 0) { W = wqp; rowbase = 2048; }
      else { W = wkp; rowbase = 2144; }
    }
    const int k0 = kt * 64, n0 = nt * 64;
    const int c = tid & 63;
#pragma unroll
    for (int ii = 0; ii < 16; ++ii) {
      int r = ii * 4 + (tid >> 6);
      float val = (n0 + c < Ncols) ? W[(size_t)(k0 + r) * Ncols + n0 + c] : 0.f;
      sm.prep.lh[r][c] = f2bf(val);
    }
    __syncthreads();
    const int n = tid >> 2, kq = tid & 3;
    if (n0 + n < Ncols) {
      unsigned short th[16] __attribute__((aligned(16)));
#pragma unroll
      for (int kk = 0; kk < 16; ++kk) th[kk] = sm.prep.lh[kq * 16 + kk][n];
      unsigned short* dh = &wt_h[(size_t)(rowbase + n0 + n) * 512 + k0 + kq * 16];
      *(int4*)dh = *(int4*)&th[0];
      *(int4*)(dh + 8) = *(int4*)&th[8];
    }
    __syncthreads();  // protect lh vs next virtual iteration
  }
}

// ---------------- MFMA core ----------------
template <int MF, int NF, int TERMS>
__device__ __forceinline__ void mfma_core(
    const unsigned short* __restrict__ Ah, const unsigned short* __restrict__ Al,
    const unsigned short* __restrict__ Bt, int mw, int nw, int Nrows,
    int ks0, int ks1, fx4 acc[MF][NF]) {
  const int lane = threadIdx.x & 63;
  const int quad = lane >> 4, l16 = lane & 15;
#pragma unroll
  for (int i = 0; i < MF; ++i)
#pragma unroll
    for (int j = 0; j < NF; ++j) acc[i][j] = (fx4){0.f, 0.f, 0.f, 0.f};
  size_t boff[NF];
#pragma unroll
  for (int j = 0; j < NF; ++j) {
    int n = nw + j * 16 + l16;
    if (n > Nrows - 1) n = Nrows - 1;
    boff[j] = (size_t)n * 512 + quad * 8;
  }
  for (int ks = ks0; ks < ks1; ++ks) {
    const int k = ks * 32 + quad * 8;
    s16x8 ah[MF], al[MF], b[NF];
#pragma unroll
    for (int i = 0; i < MF; ++i) {
      size_t off = (size_t)(mw + i * 16 + l16) * 512 + k;
      ah[i] = ldfrag(&Ah[off]);
      if (TERMS == 2) al[i] = ldfrag(&Al[off]);
    }
#pragma unroll
    for (int j = 0; j < NF; ++j) b[j] = ldfrag(&Bt[boff[j] + (size_t)ks * 32]);
#pragma unroll
    for (int i = 0; i < MF; ++i)
#pragma unroll
      for (int j = 0; j < NF; ++j) {
        acc[i][j] = __builtin_amdgcn_mfma_f32_16x16x32_bf16(ah[i], b[j], acc[i][j], 0, 0, 0);
        if (TERMS == 2)
          acc[i][j] = __builtin_amdgcn_mfma_f32_16x16x32_bf16(al[i], b[j], acc[i][j], 0, 0, 0);
      }
  }
}

// ---------------- P1: fused projections (vb = by*28 + bx, 896 total) ----------------
__device__ void proj_body(int vb, const unsigned short* __restrict__ xh,
                          const unsigned short* __restrict__ xl,
                          const unsigned short* __restrict__ wt_h,
                          const float* __restrict__ bq, const float* __restrict__ bk,
                          const float* __restrict__ bv, const float* __restrict__ bqp,
                          const float* __restrict__ bkp, const float* __restrict__ pscale,
                          unsigned short* __restrict__ qt, unsigned short* __restrict__ kt_,
                          unsigned short* __restrict__ vth, SAll& sm) {
  const int by = vb / 28;
  const int bx = vb - by * 28;
  const int m0 = by * 64;
  const int tid = threadIdx.x;
  const int wave = __builtin_amdgcn_readfirstlane(tid >> 6);
  const int lane = tid & 63;
  const int quad = lane >> 4, l16 = lane & 15;
  const int mw = m0 + (wave & 1) * 32;

  if (bx < 16) {  // q or k scalar: hi-only
    const bool isq = bx < 8;
    const float* bias = isq ? bq : bk;
    unsigned short* pdst = isq ? qt : kt_;
    const int n0 = (bx & 7) * 64;
    const int nw = n0 + (wave >> 1) * 32;
    fx4 acc[2][2];
    mfma_core<2, 2, 1>(xh, xh, wt_h + (isq ? 0 : (size_t)512 * 512), mw, nw, 512,
                       0, 16, acc);
#pragma unroll
    for (int j = 0; j < 2; ++j) {
      int n = nw + j * 16 + l16;
      int h = n >> 6, d = n & 63;
      float bb = bias[n];
#pragma unroll
      for (int i = 0; i < 2; ++i)
#pragma unroll
        for (int reg = 0; reg < 4; ++reg) {
          int row = mw + i * 16 + quad * 4 + reg;
          int bi = row >> 10, l = row & 1023;
          float val = (acc[i][j][reg] + bb) * 0.35355339059f;  // 1/sqrt(8)
          pdst[((size_t)((bi * 8 + h) * 1024 + l)) * 96 + d] = f2bf(val);
        }
    }
  } else if (bx < 24) {  // v: split-A, one head per block -> vth via LDS transpose
    const int h = bx - 16;
    const int nw = h * 64 + (wave >> 1) * 32;
    fx4 acc[2][2];
    mfma_core<2, 2, 2>(xh, xl, wt_h + (size_t)1024 * 512, mw, nw, 512, 0, 16, acc);
#pragma unroll
    for (int j = 0; j < 2; ++j) {
      int dl = (wave >> 1) * 32 + j * 16 + l16;
      float bb = bv[h * 64 + dl];
#pragma unroll
      for (int i = 0; i < 2; ++i)
#pragma unroll
        for (int reg = 0; reg < 4; ++reg) {
          int lm = (wave & 1) * 32 + i * 16 + quad * 4 + reg;
          sm.proj.vt[lm][dl] = f2bf(acc[i][j][reg] + bb);
        }
    }
    __syncthreads();
    const int b = m0 >> 10, l0 = m0 & 1023;
    const int bh = b * 8 + h;
    const int d = tid >> 2, lg = tid & 3;
    unsigned short th[16] __attribute__((aligned(16)));
#pragma unroll
    for (int kk = 0; kk < 16; ++kk) th[kk] = sm.proj.vt[lg * 16 + kk][d];
    unsigned short* dst = &vth[((size_t)(bh * 64 + d)) * LL + l0 + lg * 16];
    *(int4*)dst = *(int4*)&th[0];
    *(int4*)(dst + 8) = *(int4*)&th[8];
  } else {  // qp / kp point: hi-only
    const bool isq = bx < 26;
    const float* bias = isq ? bqp : bkp;
    unsigned short* pdst = isq ? qt : kt_;
    const int n0 = (bx & 1) * 64;
    const int nw = n0 + (wave >> 1) * 32;
    fx4 acc[2][2];
    mfma_core<2, 2, 1>(xh, xh, wt_h + (isq ? (size_t)2048 : (size_t)2144) * 512,
                       mw, nw, 96, 0, 16, acc);
#pragma unroll
    for (int j = 0; j < 2; ++j) {
      int n = nw + j * 16 + l16;
      bool ok = n < 96;
      int nn = ok ? n : 0;
      int h = nn / 12, c = nn - h * 12;
      float sc = sqrtf(2.f * pscale[h]);
      float bb = bias[nn];
#pragma unroll
      for (int i = 0; i < 2; ++i)
#pragma unroll
        for (int reg = 0; reg < 4; ++reg) {
          int row = mw + i * 16 + quad * 4 + reg;
          int bi = row >> 10, l = row & 1023;
          float val = (acc[i][j][reg] + bb) * sc;
          if (ok)
            pdst[((size_t)((bi * 8 + h) * 1024 + l)) * 96 + 64 + c] = f2bf(val);
        }
    }
  }
}

// ---------------- P2: flash IPA attention (vb = ((ksz*16)+bh)*32 + qtile, 2048) ----------------
__device__ void ipa_body(int vb, const unsigned short* __restrict__ qt,
                         const unsigned short* __restrict__ kt_,
                         const unsigned short* __restrict__ vth,
                         float* __restrict__ po, float* __restrict__ pm,
                         float* __restrict__ pl, SAll& sm) {
  const int qtile = vb & 31;
  const int bh = (vb >> 5) & 15;
  const int ksz = vb >> 9;
  const int tid = threadIdx.x;
  const int wave = tid >> 6, lane = tid & 63;
  const int quad = lane >> 4, l16 = lane & 15;
  const int mstrip = wave & 1, khalf = wave >> 1;
  const int ibase = qtile * 32 + mstrip * 16;

  s16x8 aq[3];
#pragma unroll
  for (int s = 0; s < 3; ++s)
    aq[s] = ldfrag(&qt[(size_t)(bh * LL + ibase + l16) * 96 + s * 32 + quad * 8]);

  {
    float qp = 0.f;
#pragma unroll
    for (int j = 0; j < 8; ++j) {
      float v = bf2f((unsigned short)aq[2][j]);
      qp += v * v;
    }
    qp += __shfl_xor(qp, 16);
    qp += __shfl_xor(qp, 32);
    sm.ipa.qsl[wave][l16] = 0.5f * qp;  // wave-private
  }
  float qs_r[4];
#pragma unroll
  for (int reg = 0; reg < 4; ++reg) qs_r[reg] = sm.ipa.qsl[wave][quad * 4 + reg];

  fx4 o[4];
#pragma unroll
  for (int f = 0; f < 4; ++f) o[f] = (fx4){0.f, 0.f, 0.f, 0.f};
  float m_r[4], l_r[4];
#pragma unroll
  for (int reg = 0; reg < 4; ++reg) { m_r[reg] = -INFINITY; l_r[reg] = 0.f; }

  for (int kt2 = ksz * 4; kt2 < ksz * 4 + 4; ++kt2) {
    const int j0 = kt2 * 64 + khalf * 32;
    s16x8 bk[2][3];
#pragma unroll
    for (int f = 0; f < 2; ++f)
#pragma unroll
      for (int s = 0; s < 3; ++s)
        bk[f][s] = ldfrag(&kt_[(size_t)(bh * LL + j0 + f * 16 + l16) * 96 + s * 32 + quad * 8]);
    s16x8 bvh[4];
#pragma unroll
    for (int f = 0; f < 4; ++f)
      bvh[f] = ldfrag(&vth[((size_t)(bh * 64 + f * 16 + l16)) * LL + j0 + quad * 8]);

    float kp0 = 0.f, kp1 = 0.f;
#pragma unroll
    for (int j = 0; j < 8; ++j) {
      float v0 = bf2f((unsigned short)bk[0][2][j]);
      float v1 = bf2f((unsigned short)bk[1][2][j]);
      kp0 += v0 * v0;
      kp1 += v1 * v1;
    }
    kp0 += __shfl_xor(kp0, 16);
    kp0 += __shfl_xor(kp0, 32);
    kp1 += __shfl_xor(kp1, 16);
    kp1 += __shfl_xor(kp1, 32);
    float ks0 = 0.5f * kp0, ks1 = 0.5f * kp1;

    fx4 sa[2];
    sa[0] = (fx4){0.f, 0.f, 0.f, 0.f};
    sa[1] = (fx4){0.f, 0.f, 0.f, 0.f};
#pragma unroll
    for (int f = 0; f < 2; ++f)
#pragma unroll
      for (int s = 0; s < 3; ++s)
        sa[f] = __builtin_amdgcn_mfma_f32_16x16x32_bf16(aq[s], bk[f][s], sa[f], 0, 0, 0);

#pragma unroll
    for (int reg = 0; reg < 4; ++reg) {
      float z0 = sa[0][reg] - qs_r[reg] - ks0;
      float z1 = sa[1][reg] - qs_r[reg] - ks1;
      float mx = red16_max(fmaxf(z0, z1));
      float mnew = fmaxf(m_r[reg], mx);
      float p0 = __expf(z0 - mnew), p1 = __expf(z1 - mnew);
      float alpha = __expf(m_r[reg] - mnew);
      float psum = red16_sum(p0 + p1);
      l_r[reg] = l_r[reg] * alpha + psum;
      m_r[reg] = mnew;
      o[0][reg] *= alpha; o[1][reg] *= alpha; o[2][reg] *= alpha; o[3][reg] *= alpha;
      sm.ipa.pb[wave][quad * 4 + reg][l16] = f2bf(p0);
      sm.ipa.pb[wave][quad * 4 + reg][16 + l16] = f2bf(p1);
    }
    s16x8 ap = ldfrag(&sm.ipa.pb[wave][l16][quad * 8]);
#pragma unroll
    for (int f = 0; f < 4; ++f)
      o[f] = __builtin_amdgcn_mfma_f32_16x16x32_bf16(ap, bvh[f], o[f], 0, 0, 0);
  }
  if (l16 == 0) {
#pragma unroll
    for (int reg = 0; reg < 4; ++reg) {
      sm.ipa.mred[wave][quad * 4 + reg] = m_r[reg];
      sm.ipa.lred[wave][quad * 4 + reg] = l_r[reg];
    }
  }
#pragma unroll
  for (int f = 0; f < 4; ++f)
#pragma unroll
    for (int reg = 0; reg < 4; ++reg)
      sm.ipa.obuf[wave][quad * 4 + reg][f * 16 + l16] = o[f][reg];
  __syncthreads();
  if (khalf == 0) {
    const int pw = wave + 2;
    const size_t rbase = ((size_t)ksz * 16 + bh) * LL + ibase;
#pragma unroll
    for (int f = 0; f < 4; ++f)
#pragma unroll
      for (int reg = 0; reg < 4; ++reg) {
        int row = quad * 4 + reg;
        int d = f * 16 + l16;
        float m0v = sm.ipa.mred[wave][row], m1v = sm.ipa.mred[pw][row];
        float l0v = sm.ipa.lred[wave][row], l1v = sm.ipa.lred[pw][row];
        float M = fmaxf(m0v, m1v);
        float w0 = __expf(m0v - M), w1 = __expf(m1v - M);
        float Lv = l0v * w0 + l1v * w1;
        float val = sm.ipa.obuf[wave][row][d] * w0 + sm.ipa.obuf[pw][row][d] * w1;
        po[(rbase + row) * 64 + d] = val;
        if (f == 0 && l16 == 0) {
          pm[rbase + row] = M;
          pl[rbase + row] = Lv;
        }
      }
  }
  __syncthreads();  // protect obuf/mred/lred vs next virtual iteration
}

// ---------------- P3: merge 4 K-split partials (vb 0..4095) ----------------
__device__ void merge_body(int vb, const float* __restrict__ po,
                           const float* __restrict__ pm, const float* __restrict__ pl,
                           unsigned short* __restrict__ oh, unsigned short* __restrict__ ol) {
  const int r = vb * 4 + (threadIdx.x >> 6);
  const int lane = threadIdx.x & 63;
  const size_t part = (size_t)16 * LL;
  float M = -INFINITY;
#pragma unroll
  for (int p = 0; p < 4; ++p) M = fmaxf(M, pm[p * part + r]);
  float L = 0.f, v = 0.f;
#pragma unroll
  for (int p = 0; p < 4; ++p) {
    float w = __expf(pm[p * part + r] - M);
    L += pl[p * part + r] * w;
    v += po[(p * part + r) * 64 + lane] * w;
  }
  v /= L;
  int bh = r >> 10, l = r & 1023;
  int b = bh >> 3, h = bh & 7;
  size_t addr = ((size_t)(b * LL + l)) * CCH + h * 64 + lane;
  unsigned short hv = f2bf(v);
  oh[addr] = hv;
  ol[addr] = f2bf(v - bf2f(hv));
}

// ---------------- P4: output projection (vb = ((kz*32)+by)*8 + nx, 1024) ----------------
__device__ void outproj_body(int vb, const unsigned short* __restrict__ oh,
                             const unsigned short* __restrict__ ol,
                             const unsigned short* __restrict__ wt_h,
                             const float* __restrict__ bo, float* __restrict__ out) {
  const int nx = vb & 7;
  const int by = (vb >> 3) & 31;
  const int kz = vb >> 8;
  const int tid = threadIdx.x;
  const int wave = __builtin_amdgcn_readfirstlane(tid >> 6);
  const int lane = tid & 63;
  const int quad = lane >> 4, l16 = lane & 15;
  const int mw = by * 64 + (wave & 1) * 32;
  const int nw = nx * 64 + (wave >> 1) * 32;
  fx4 acc[2][2];
  mfma_core<2, 2, 2>(oh, ol, wt_h + (size_t)1536 * 512, mw, nw, 512, kz * 4,
                     kz * 4 + 4, acc);
#pragma unroll
  for (int j = 0; j < 2; ++j) {
    int n = nw + j * 16 + l16;
    float bb = (kz == 0) ? bo[n] : 0.f;
#pragma unroll
    for (int i = 0; i < 2; ++i)
#pragma unroll
      for (int reg = 0; reg < 4; ++reg) {
        int row = mw + i * 16 + quad * 4 + reg;
        atomicAdd(&out[(size_t)row * 512 + n], acc[i][j][reg] + bb);
      }
  }
}

// ---------------- persistent mega-kernel: 1024 blocks x 256 thr, 4 blocks/CU ----------------
__global__ __launch_bounds__(256, 4) void mega(
    const float* features, const float* ln_g, const float* ln_b,
    const float* wq, const float* bq, const float* wk, const float* bk,
    const float* wv, const float* bv, const float* wqp, const float* bqp,
    const float* wkp, const float* bkp, const float* bo, const float* pscale,
    unsigned short* xh, unsigned short* xl, unsigned short* wt_h,
    unsigned short* qt, unsigned short* kt_, unsigned short* vth,
    unsigned short* oh, unsigned short* ol, float* po, float* pm, float* pl,
    float* out, int* bar) {
  __shared__ SAll sm;
  const int bid = blockIdx.x;
  const int tid = threadIdx.x;

  // P0: prep (2336) + zero out (1024) + zero qt/kt pads (512) = 3872
  for (int vb = bid; vb < 3872; vb += NBLK) {
    if (vb < 2336) {
      prep_body(vb, features, ln_g, ln_b, xh, xl, wq, wk, wv,
                /*wo=*/bo /*placeholder, fixed below*/, wqp, wkp, wt_h, sm);
    } else if (vb < 3360) {
      int z = vb - 2336;
      float4 zero = {0.f, 0.f, 0.f, 0.f};
      ((float4*)out)[(size_t)z * 256 + tid] = zero;
    } else {
      int z = vb - 3360;
      unsigned short* dst = (z < 256) ? qt : kt_;
      int row = (z & 255) * 64 + (tid >> 2);
      int c = tid & 3;
      int4 zero = {0, 0, 0, 0};
      *(int4*)&dst[(size_t)row * 96 + 64 + c * 8] = zero;
    }
  }
  grid_barrier(bar);
  // P1: projections (896)
  for (int vb = bid; vb < 896; vb += NBLK)
    proj_body(vb, xh, xl, wt_h, bq, bk, bv, bqp, bkp, pscale, qt, kt_, vth, sm);
  grid_barrier(bar);
  // P2: attention (2048)
  for (int vb = bid; vb < 2048; vb += NBLK)
    ipa_body(vb, qt, kt_, vth, po, pm, pl, sm);
  grid_barrier(bar);
  // P3: merge (4096)
  for (int vb = bid; vb < 4096; vb += NBLK)
    merge_body(vb, po, pm, pl, oh, ol);
  grid_barrier(bar);
  // P4: output projection (1024)
  for (int vb = bid; vb < 1024; vb += NBLK)
    outproj_body(vb, oh, ol, wt_h, bo, out);
}

// NOTE: prep_body's wo parameter was accidentally wired to bo above; fix by
// passing wo through an extra kernel arg. To keep one definition, mega2 below
// is the real entry (mega kept unused to avoid refactoring churn is NOT ok) —
// instead we define the kernel properly here:
__global__ __launch_bounds__(256, 4) void mega_k(
    const float* features, const float* ln_g, const float* ln_b,
    const float* wq, const float* bq, const float* wk, const float* bk,
    const float* wv, const float* bv, const float* wqp, const float* bqp,
    const float* wkp, const float* bkp, const float* wo, const float* bo,
    const float* pscale, unsigned short* xh, unsigned short* xl,
    unsigned short* wt_h, unsigned short* qt, unsigned short* kt_,
    unsigned short* vth, unsigned short* oh, unsigned short* ol, float* po,
    float* pm, float* pl, float* out, int* bar) {
  __shared__ SAll sm;
  const int bid = blockIdx.x;
  const int tid = threadIdx.x;

  for (int vb = bid; vb < 3872; vb += NBLK) {
    if (vb < 2336) {
      prep_body(vb, features, ln_g, ln_b, xh, xl, wq, wk, wv, wo, wqp, wkp, wt_h, sm);
    } else if (vb < 3360) {
      int z = vb - 2336;
      float4 zero = {0.f, 0.f, 0.f, 0.f};
      ((float4*)out)[(size_t)z * 256 + tid] = zero;
    } else {
      int z = vb - 3360;
      unsigned short* dst = (z < 256) ? qt : kt_;
      int row = (z & 255) * 64 + (tid >> 2);
      int c = tid & 3;
      int4 zero = {0, 0, 0, 0};
      *(int4*)&dst[(size_t)row * 96 + 64 + c * 8] = zero;
    }
  }
  grid_barrier(bar);
  for (int vb = bid; vb < 896; vb += NBLK)
    proj_body(vb, xh, xl, wt_h, bq, bk, bv, bqp, bkp, pscale, qt, kt_, vth, sm);
  grid_barrier(bar);
  for (int vb = bid; vb < 2048; vb += NBLK)
    ipa_body(vb, qt, kt_, vth, po, pm, pl, sm);
  grid_barrier(bar);
  for (int vb = bid; vb < 4096; vb += NBLK)
    merge_body(vb, po, pm, pl, oh, ol);
  grid_barrier(bar);
  for (int vb = bid; vb < 1024; vb += NBLK)
    outproj_body(vb, oh, ol, wt_h, bo, out);
}

extern "C" void kernel_launch(void* const* d_in, const int* in_sizes, int n_in,
                              void* d_out, int out_size, void* d_ws, size_t ws_size,
                              hipStream_t stream) {
  (void)in_sizes; (void)n_in; (void)out_size; (void)ws_size;
  const float* features = (const float*)d_in[0];
  const float* ln_g = (const float*)d_in[2];
  const float* ln_b = (const float*)d_in[3];
  const float* wq = (const float*)d_in[4];
  const float* bq = (const float*)d_in[5];
  const float* wk = (const float*)d_in[6];
  const float* bk = (const float*)d_in[7];
  const float* wv = (const float*)d_in[8];
  const float* bv = (const float*)d_in[9];
  const float* wqp = (const float*)d_in[10];
  const float* bqp = (const float*)d_in[11];
  const float* wkp = (const float*)d_in[12];
  const float* bkp = (const float*)d_in[13];
  const float* wo = (const float*)d_in[16];
  const float* bo = (const float*)d_in[17];
  const float* pscale = (const float*)d_in[18];
  float* out = (float*)d_out;

  char* cur = (char*)d_ws;
  const size_t NTOK = (size_t)BB * LL;  // 2048
  unsigned short* xh = (unsigned short*)cur; cur += NTOK * CCH * 2;
  unsigned short* xl = (unsigned short*)cur; cur += NTOK * CCH * 2;
  unsigned short* wt_h = (unsigned short*)cur; cur += (size_t)2240 * 512 * 2;
  unsigned short* qt = (unsigned short*)cur; cur += (size_t)16 * LL * 96 * 2;
  unsigned short* kt_ = (unsigned short*)cur; cur += (size_t)16 * LL * 96 * 2;
  unsigned short* vth = (unsigned short*)cur; cur += (size_t)16 * 64 * LL * 2;
  unsigned short* oh = (unsigned short*)cur; cur += NTOK * CCH * 2;
  unsigned short* ol = (unsigned short*)cur; cur += NTOK * CCH * 2;
  float* po = (float*)cur; cur += (size_t)4 * 16 * LL * 64 * 4;
  float* pm = (float*)cur; cur += (size_t)4 * 16 * LL * 4;
  float* pl = (float*)cur; cur += (size_t)4 * 16 * LL * 4;
  int* bar = (int*)cur; cur += 16;

  hipMemsetAsync(bar, 0, 8, stream);  // barrier {count, generation}

  mega_k<<<dim3(NBLK), 256, 0, stream>>>(
      features, ln_g, ln_b, wq, bq, wk, bk, wv, bv, wqp, bqp, wkp, bkp, wo, bo,
      pscale, xh, xl, wt_h, qt, kt_, vth, oh, ol, po, pm, pl, out, bar);
}

// Round 10
// 195.604 us; speedup vs baseline: 5.4217x; 5.4217x over previous
//
#include <hip/hip_runtime.h>
#include <math.h>

#define BB 2
#define LL 1024
#define CCH 512
#define HH 8
#define LN_EPSF 1e-5f

typedef short s16x8 __attribute__((ext_vector_type(8)));
typedef float fx4 __attribute__((ext_vector_type(4)));

__device__ __forceinline__ unsigned short f2bf(float f) {
  unsigned u = __float_as_uint(f);
  unsigned r = (u + 0x7FFFu + ((u >> 16) & 1u)) >> 16;
  return (unsigned short)r;
}
__device__ __forceinline__ float bf2f(unsigned short h) {
  return __uint_as_float(((unsigned)h) << 16);
}
__device__ __forceinline__ s16x8 ldfrag(const unsigned short* p) {
  int4 t = *(const int4*)p;
  return *(s16x8*)&t;
}

// ---- DPP row_ror reductions over 16-lane rows ----
template <int CTRL>
__device__ __forceinline__ float dpp_mov(float x) {
  return __int_as_float(
      __builtin_amdgcn_update_dpp(0, __float_as_int(x), CTRL, 0xF, 0xF, true));
}
__device__ __forceinline__ float red16_sum(float v) {
  v += dpp_mov<0x121>(v);
  v += dpp_mov<0x122>(v);
  v += dpp_mov<0x124>(v);
  v += dpp_mov<0x128>(v);
  return v;
}
__device__ __forceinline__ float red16_max(float v) {
  v = fmaxf(v, dpp_mov<0x121>(v));
  v = fmaxf(v, dpp_mov<0x122>(v));
  v = fmaxf(v, dpp_mov<0x124>(v));
  v = fmaxf(v, dpp_mov<0x128>(v));
  return v;
}
__device__ __forceinline__ float wave_sum(float v) {
  v = red16_sum(v);
  v += __shfl_xor(v, 16);
  v += __shfl_xor(v, 32);
  return v;
}

// ---------------- prep: LayerNorm (blocks 0..2047) + weight pack (2048..2335) ----------------
// ln: features -> split bf16 xh/xl.  pack: W[k][n] fp32 -> Wt[n][k] bf16 hi.
// wt row map: q:0, k:512, v:1024, o:1536, qp:2048(+96), kp:2144(+96)
__global__ __launch_bounds__(256) void prep(
    const float* __restrict__ f, const float* __restrict__ g,
    const float* __restrict__ bta, unsigned short* __restrict__ xh,
    unsigned short* __restrict__ xl, const float* __restrict__ wq,
    const float* __restrict__ wk, const float* __restrict__ wv,
    const float* __restrict__ wo, const float* __restrict__ wqp,
    const float* __restrict__ wkp, unsigned short* __restrict__ wt_h) {
  __shared__ unsigned short lh[64][68];
  __shared__ float red[8];
  const int tid = threadIdx.x;
  if (blockIdx.x < 2048) {  // ---- LayerNorm ----
    const int row = blockIdx.x;
    const int wave = tid >> 6, lane = tid & 63;
    const float* fr = f + (size_t)row * CCH;
    float2 v = *(const float2*)&fr[tid * 2];
    float s = wave_sum(v.x + v.y);
    if (lane == 0) red[wave] = s;
    __syncthreads();
    float mu = (red[0] + red[1] + red[2] + red[3]) * (1.0f / CCH);
    float dx = v.x - mu, dy = v.y - mu;
    float sq = wave_sum(dx * dx + dy * dy);
    if (lane == 0) red[4 + wave] = sq;
    __syncthreads();
    float var = (red[4] + red[5] + red[6] + red[7]) * (1.0f / CCH);
    float inv = 1.0f / sqrtf(var + LN_EPSF);
    float2 gg = *(const float2*)&g[tid * 2];
    float2 bb = *(const float2*)&bta[tid * 2];
    float ox = dx * inv * gg.x + bb.x;
    float oy = dy * inv * gg.y + bb.y;
    unsigned short h0 = f2bf(ox), h1 = f2bf(oy);
    ushort2 hv; hv.x = h0; hv.y = h1;
    ushort2 lv; lv.x = f2bf(ox - bf2f(h0)); lv.y = f2bf(oy - bf2f(h1));
    *(ushort2*)&xh[(size_t)row * CCH + tid * 2] = hv;
    *(ushort2*)&xl[(size_t)row * CCH + tid * 2] = lv;
  } else {  // ---- weight pack ----
    const int bx = blockIdx.x - 2048;
    const float* W;
    int Ncols, rowbase, kt, nt;
    if (bx < 256) {
      int mat = bx >> 6, t = bx & 63;
      kt = t >> 3; nt = t & 7; Ncols = 512;
      if (mat == 0) { W = wq; rowbase = 0; }
      else if (mat == 1) { W = wk; rowbase = 512; }
      else if (mat == 2) { W = wv; rowbase = 1024; }
      else { W = wo; rowbase = 1536; }
    } else {
      int r = bx - 256; int mat = r >> 4; int t = r & 15;
      kt = t >> 1; nt = t & 1; Ncols = 96;
      if (mat == 0) { W = wqp; rowbase = 2048; }
      else { W = wkp; rowbase = 2144; }
    }
    const int k0 = kt * 64, n0 = nt * 64;
    const int c = tid & 63;
#pragma unroll
    for (int ii = 0; ii < 16; ++ii) {
      int r = ii * 4 + (tid >> 6);
      float val = (n0 + c < Ncols) ? W[(size_t)(k0 + r) * Ncols + n0 + c] : 0.f;
      lh[r][c] = f2bf(val);
    }
    __syncthreads();
    const int n = tid >> 2, kq = tid & 3;
    if (n0 + n < Ncols) {
      unsigned short th[16] __attribute__((aligned(16)));
#pragma unroll
      for (int kk = 0; kk < 16; ++kk) th[kk] = lh[kq * 16 + kk][n];
      unsigned short* dh = &wt_h[(size_t)(rowbase + n0 + n) * 512 + k0 + kq * 16];
      *(int4*)dh = *(int4*)&th[0];
      *(int4*)(dh + 8) = *(int4*)&th[8];
    }
  }
}

// ---------------- MFMA core: acc[MF][NF] over rows mw.., cols nw.. ----------------
// TERMS=1: Ah@B.  TERMS=2: (Ah+Al)@B (split-A, single-B).
template <int MF, int NF, int TERMS>
__device__ __forceinline__ void mfma_core(
    const unsigned short* __restrict__ Ah, const unsigned short* __restrict__ Al,
    const unsigned short* __restrict__ Bt, int mw, int nw, int Nrows,
    int ks0, int ks1, fx4 acc[MF][NF]) {
  const int lane = threadIdx.x & 63;
  const int quad = lane >> 4, l16 = lane & 15;
#pragma unroll
  for (int i = 0; i < MF; ++i)
#pragma unroll
    for (int j = 0; j < NF; ++j) acc[i][j] = (fx4){0.f, 0.f, 0.f, 0.f};
  size_t boff[NF];
#pragma unroll
  for (int j = 0; j < NF; ++j) {
    int n = nw + j * 16 + l16;
    if (n > Nrows - 1) n = Nrows - 1;
    boff[j] = (size_t)n * 512 + quad * 8;
  }
  for (int ks = ks0; ks < ks1; ++ks) {
    const int k = ks * 32 + quad * 8;
    s16x8 ah[MF], al[MF], b[NF];
#pragma unroll
    for (int i = 0; i < MF; ++i) {
      size_t off = (size_t)(mw + i * 16 + l16) * 512 + k;
      ah[i] = ldfrag(&Ah[off]);
      if (TERMS == 2) al[i] = ldfrag(&Al[off]);
    }
#pragma unroll
    for (int j = 0; j < NF; ++j) b[j] = ldfrag(&Bt[boff[j] + (size_t)ks * 32]);
#pragma unroll
    for (int i = 0; i < MF; ++i)
#pragma unroll
      for (int j = 0; j < NF; ++j) {
        acc[i][j] = __builtin_amdgcn_mfma_f32_16x16x32_bf16(ah[i], b[j], acc[i][j], 0, 0, 0);
        if (TERMS == 2)
          acc[i][j] = __builtin_amdgcn_mfma_f32_16x16x32_bf16(al[i], b[j], acc[i][j], 0, 0, 0);
      }
  }
}

// ---------------- Fused projections, 64x64 blocks. grid (28, 32) ----------------
// bx 0..7: q -> qt pack; 8..15: k -> kt; 16..23: v (head h=bx-16) -> vth direct
// via LDS transpose; 24,25: qp cols 0-63/64-95; 26,27: kp.
__global__ __launch_bounds__(256, 4) void proj_mfma(
    const unsigned short* __restrict__ xh, const unsigned short* __restrict__ xl,
    const unsigned short* __restrict__ wt_h,
    const float* __restrict__ bq, const float* __restrict__ bk,
    const float* __restrict__ bv, const float* __restrict__ bqp,
    const float* __restrict__ bkp, const float* __restrict__ pscale,
    unsigned short* __restrict__ qt, unsigned short* __restrict__ kt_,
    unsigned short* __restrict__ vth) {
  __shared__ unsigned short vt_lds[64][72];
  const int bx = blockIdx.x;
  const int m0 = blockIdx.y * 64;
  const int tid = threadIdx.x;
  const int wave = __builtin_amdgcn_readfirstlane(tid >> 6);
  const int lane = tid & 63;
  const int quad = lane >> 4, l16 = lane & 15;
  const int mw = m0 + (wave & 1) * 32;

  if (bx < 16) {  // q or k scalar: hi-only
    const bool isq = bx < 8;
    const float* bias = isq ? bq : bk;
    unsigned short* pdst = isq ? qt : kt_;
    const int n0 = (bx & 7) * 64;
    const int nw = n0 + (wave >> 1) * 32;
    fx4 acc[2][2];
    mfma_core<2, 2, 1>(xh, xh, wt_h + (isq ? 0 : (size_t)512 * 512), mw, nw, 512,
                       0, 16, acc);
#pragma unroll
    for (int j = 0; j < 2; ++j) {
      int n = nw + j * 16 + l16;
      int h = n >> 6, d = n & 63;
      float bb = bias[n];
#pragma unroll
      for (int i = 0; i < 2; ++i)
#pragma unroll
        for (int reg = 0; reg < 4; ++reg) {
          int row = mw + i * 16 + quad * 4 + reg;
          int bi = row >> 10, l = row & 1023;
          float val = (acc[i][j][reg] + bb) * 0.35355339059f;  // 1/sqrt(8)
          pdst[((size_t)((bi * 8 + h) * 1024 + l)) * 96 + d] = f2bf(val);
        }
    }
  } else if (bx < 24) {  // v: split-A, one head per block -> vth via LDS transpose
    const int h = bx - 16;
    const int nw = h * 64 + (wave >> 1) * 32;
    fx4 acc[2][2];
    mfma_core<2, 2, 2>(xh, xl, wt_h + (size_t)1024 * 512, mw, nw, 512, 0, 16, acc);
#pragma unroll
    for (int j = 0; j < 2; ++j) {
      int dl = (wave >> 1) * 32 + j * 16 + l16;
      float bb = bv[h * 64 + dl];
#pragma unroll
      for (int i = 0; i < 2; ++i)
#pragma unroll
        for (int reg = 0; reg < 4; ++reg) {
          int lm = (wave & 1) * 32 + i * 16 + quad * 4 + reg;
          vt_lds[lm][dl] = f2bf(acc[i][j][reg] + bb);
        }
    }
    __syncthreads();
    const int b = m0 >> 10, l0 = m0 & 1023;
    const int bh = b * 8 + h;
    const int d = tid >> 2, lg = tid & 3;
    unsigned short th[16] __attribute__((aligned(16)));
#pragma unroll
    for (int kk = 0; kk < 16; ++kk) th[kk] = vt_lds[lg * 16 + kk][d];
    unsigned short* dst = &vth[((size_t)(bh * 64 + d)) * LL + l0 + lg * 16];
    *(int4*)dst = *(int4*)&th[0];
    *(int4*)(dst + 8) = *(int4*)&th[8];
  } else {  // qp / kp point: hi-only
    const bool isq = bx < 26;
    const float* bias = isq ? bqp : bkp;
    unsigned short* pdst = isq ? qt : kt_;
    const int n0 = (bx & 1) * 64;
    const int nw = n0 + (wave >> 1) * 32;
    fx4 acc[2][2];
    mfma_core<2, 2, 1>(xh, xh, wt_h + (isq ? (size_t)2048 : (size_t)2144) * 512,
                       mw, nw, 96, 0, 16, acc);
#pragma unroll
    for (int j = 0; j < 2; ++j) {
      int n = nw + j * 16 + l16;
      bool ok = n < 96;
      int nn = ok ? n : 0;
      int h = nn / 12, c = nn - h * 12;
      float sc = sqrtf(2.f * pscale[h]);
      float bb = bias[nn];
#pragma unroll
      for (int i = 0; i < 2; ++i)
#pragma unroll
        for (int reg = 0; reg < 4; ++reg) {
          int row = mw + i * 16 + quad * 4 + reg;
          int bi = row >> 10, l = row & 1023;
          float val = (acc[i][j][reg] + bb) * sc;
          if (ok)
            pdst[((size_t)((bi * 8 + h) * 1024 + l)) * 96 + 64 + c] = f2bf(val);
        }
    }
  }
}

// ---------------- Output projection: hi-only A, K-split x4, atomic accumulate ----------------
// grid (8, 32, 4): 64x64 tile, K quarter per z. out must be pre-zeroed.
__global__ __launch_bounds__(256, 4) void out_proj_mfma(
    const unsigned short* __restrict__ oh,
    const unsigned short* __restrict__ wt_h, const float* __restrict__ bo,
    float* __restrict__ out) {
  const int tid = threadIdx.x;
  const int wave = __builtin_amdgcn_readfirstlane(tid >> 6);
  const int lane = tid & 63;
  const int quad = lane >> 4, l16 = lane & 15;
  const int mw = blockIdx.y * 64 + (wave & 1) * 32;
  const int nw = blockIdx.x * 64 + (wave >> 1) * 32;
  const int kz = blockIdx.z;
  fx4 acc[2][2];
  mfma_core<2, 2, 1>(oh, oh, wt_h + (size_t)1536 * 512, mw, nw, 512, kz * 4,
                     kz * 4 + 4, acc);
#pragma unroll
  for (int j = 0; j < 2; ++j) {
    int n = nw + j * 16 + l16;
    float bb = (kz == 0) ? bo[n] : 0.f;
#pragma unroll
    for (int i = 0; i < 2; ++i)
#pragma unroll
      for (int reg = 0; reg < 4; ++reg) {
        int row = mw + i * 16 + quad * 4 + reg;
        atomicAdd(&out[(size_t)row * 512 + n], acc[i][j][reg] + bb);
      }
  }
}

// ---------------- Flash IPA attention, K-split x2, XCD-swizzled 1D grid ----------------
// 1024 blocks; bid = (qtile + 32*(ksz + 2*(bh>>3)))*8 + (bh&7) so all blocks of
// head-pair {bh, bh+8} land on one XCD (bid%8 round-robin heuristic) -> K/V/Q
// stay in that XCD's 4MB L2 (~1MB working set vs 8MB unswizzled).
// Block = 4 waves = 2 mstrips x 2 khalves; 8 key-tiles of 64 per block.
__global__ __launch_bounds__(256, 4) void ipa_attn_mfma(
    const unsigned short* __restrict__ qt, const unsigned short* __restrict__ kt_,
    const unsigned short* __restrict__ vth,
    float* __restrict__ po, float* __restrict__ pm, float* __restrict__ pl) {
  const int bid = blockIdx.x;
  const int low3 = bid & 7;
  const int slot = bid >> 3;
  const int qtile = slot & 31;
  const int t = slot >> 5;  // 0..3
  const int ksz = t & 1;
  const int bh = ((t >> 1) << 3) | low3;
  const int tid = threadIdx.x;
  const int wave = tid >> 6, lane = tid & 63;
  const int quad = lane >> 4, l16 = lane & 15;
  const int mstrip = wave & 1, khalf = wave >> 1;
  const int ibase = qtile * 32 + mstrip * 16;

  __shared__ unsigned short pb[4][16][32];
  __shared__ float obuf[4][16][64];
  __shared__ float mred[4][16], lred[4][16];
  __shared__ float qsl[4][16];

  s16x8 aq[3];
#pragma unroll
  for (int s = 0; s < 3; ++s)
    aq[s] = ldfrag(&qt[(size_t)(bh * LL + ibase + l16) * 96 + s * 32 + quad * 8]);

  // qsq for row ibase+l16: 0.5 * sum over point-slot (cols 64..95) squares
  {
    float qp = 0.f;
#pragma unroll
    for (int j = 0; j < 8; ++j) {
      float v = bf2f((unsigned short)aq[2][j]);
      qp += v * v;
    }
    qp += __shfl_xor(qp, 16);
    qp += __shfl_xor(qp, 32);
    qsl[wave][l16] = 0.5f * qp;  // wave-private; in-wave DS ordering
  }
  float qs_r[4];
#pragma unroll
  for (int reg = 0; reg < 4; ++reg) qs_r[reg] = qsl[wave][quad * 4 + reg];

  fx4 o[4];
#pragma unroll
  for (int f = 0; f < 4; ++f) o[f] = (fx4){0.f, 0.f, 0.f, 0.f};
  float m_r[4], l_r[4];
#pragma unroll
  for (int reg = 0; reg < 4; ++reg) { m_r[reg] = -INFINITY; l_r[reg] = 0.f; }

  for (int kt2 = ksz * 8; kt2 < ksz * 8 + 8; ++kt2) {
    const int j0 = kt2 * 64 + khalf * 32;
    s16x8 bk[2][3];
#pragma unroll
    for (int f = 0; f < 2; ++f)
#pragma unroll
      for (int s = 0; s < 3; ++s)
        bk[f][s] = ldfrag(&kt_[(size_t)(bh * LL + j0 + f * 16 + l16) * 96 + s * 32 + quad * 8]);
    s16x8 bvh[4];
#pragma unroll
    for (int f = 0; f < 4; ++f)
      bvh[f] = ldfrag(&vth[((size_t)(bh * 64 + f * 16 + l16)) * LL + j0 + quad * 8]);

    // ksq for keys j0+l16 (f=0) and j0+16+l16 (f=1) from the s=2 fragments
    float kp0 = 0.f, kp1 = 0.f;
#pragma unroll
    for (int j = 0; j < 8; ++j) {
      float v0 = bf2f((unsigned short)bk[0][2][j]);
      float v1 = bf2f((unsigned short)bk[1][2][j]);
      kp0 += v0 * v0;
      kp1 += v1 * v1;
    }
    kp0 += __shfl_xor(kp0, 16);
    kp0 += __shfl_xor(kp0, 32);
    kp1 += __shfl_xor(kp1, 16);
    kp1 += __shfl_xor(kp1, 32);
    float ks0 = 0.5f * kp0, ks1 = 0.5f * kp1;

    fx4 sa[2];
    sa[0] = (fx4){0.f, 0.f, 0.f, 0.f};
    sa[1] = (fx4){0.f, 0.f, 0.f, 0.f};
#pragma unroll
    for (int f = 0; f < 2; ++f)
#pragma unroll
      for (int s = 0; s < 3; ++s)
        sa[f] = __builtin_amdgcn_mfma_f32_16x16x32_bf16(aq[s], bk[f][s], sa[f], 0, 0, 0);

#pragma unroll
    for (int reg = 0; reg < 4; ++reg) {
      float z0 = sa[0][reg] - qs_r[reg] - ks0;
      float z1 = sa[1][reg] - qs_r[reg] - ks1;
      float mx = red16_max(fmaxf(z0, z1));
      float mnew = fmaxf(m_r[reg], mx);
      float p0 = __expf(z0 - mnew), p1 = __expf(z1 - mnew);
      float alpha = __expf(m_r[reg] - mnew);
      float psum = red16_sum(p0 + p1);
      l_r[reg] = l_r[reg] * alpha + psum;
      m_r[reg] = mnew;
      o[0][reg] *= alpha; o[1][reg] *= alpha; o[2][reg] *= alpha; o[3][reg] *= alpha;
      pb[wave][quad * 4 + reg][l16] = f2bf(p0);
      pb[wave][quad * 4 + reg][16 + l16] = f2bf(p1);
    }
    s16x8 ap = ldfrag(&pb[wave][l16][quad * 8]);
#pragma unroll
    for (int f = 0; f < 4; ++f)
      o[f] = __builtin_amdgcn_mfma_f32_16x16x32_bf16(ap, bvh[f], o[f], 0, 0, 0);
  }
  if (l16 == 0) {
#pragma unroll
    for (int reg = 0; reg < 4; ++reg) {
      mred[wave][quad * 4 + reg] = m_r[reg];
      lred[wave][quad * 4 + reg] = l_r[reg];
    }
  }
#pragma unroll
  for (int f = 0; f < 4; ++f)
#pragma unroll
    for (int reg = 0; reg < 4; ++reg)
      obuf[wave][quad * 4 + reg][f * 16 + l16] = o[f][reg];
  __syncthreads();
  if (khalf == 0) {
    const int pw = wave + 2;
    const size_t rbase = ((size_t)ksz * 16 + bh) * LL + ibase;
#pragma unroll
    for (int f = 0; f < 4; ++f)
#pragma unroll
      for (int reg = 0; reg < 4; ++reg) {
        int row = quad * 4 + reg;
        int d = f * 16 + l16;
        float m0v = mred[wave][row], m1v = mred[pw][row];
        float l0v = lred[wave][row], l1v = lred[pw][row];
        float M = fmaxf(m0v, m1v);
        float w0 = __expf(m0v - M), w1 = __expf(m1v - M);
        float Lv = l0v * w0 + l1v * w1;
        float val = obuf[wave][row][d] * w0 + obuf[pw][row][d] * w1;
        po[(rbase + row) * 64 + d] = val;
        if (f == 0 && l16 == 0) {
          pm[rbase + row] = M;
          pl[rbase + row] = Lv;
        }
      }
  }
}

// ---------------- Merge the 2 K-split partials -> bf16 (hi only) ----------------
__global__ __launch_bounds__(256) void merge_attn(const float* __restrict__ po,
                                                  const float* __restrict__ pm,
                                                  const float* __restrict__ pl,
                                                  unsigned short* __restrict__ oh) {
  const int r = blockIdx.x * 4 + (threadIdx.x >> 6);  // row in [0, 16*1024)
  const int lane = threadIdx.x & 63;
  const size_t part = (size_t)16 * LL;
  float m0 = pm[r], m1 = pm[part + r];
  float l0 = pl[r], l1 = pl[part + r];
  float M = fmaxf(m0, m1);
  float w0 = __expf(m0 - M), w1 = __expf(m1 - M);
  float L = l0 * w0 + l1 * w1;
  float v = (po[(size_t)r * 64 + lane] * w0 + po[(part + r) * 64 + lane] * w1) / L;
  int bh = r >> 10, l = r & 1023;
  int b = bh >> 3, h = bh & 7;
  size_t addr = ((size_t)(b * LL + l)) * CCH + h * 64 + lane;
  oh[addr] = f2bf(v);
}

extern "C" void kernel_launch(void* const* d_in, const int* in_sizes, int n_in,
                              void* d_out, int out_size, void* d_ws, size_t ws_size,
                              hipStream_t stream) {
  (void)in_sizes; (void)n_in; (void)out_size; (void)ws_size;
  const float* features = (const float*)d_in[0];
  const float* ln_g = (const float*)d_in[2];
  const float* ln_b = (const float*)d_in[3];
  const float* wq = (const float*)d_in[4];
  const float* bq = (const float*)d_in[5];
  const float* wk = (const float*)d_in[6];
  const float* bk = (const float*)d_in[7];
  const float* wv = (const float*)d_in[8];
  const float* bv = (const float*)d_in[9];
  const float* wqp = (const float*)d_in[10];
  const float* bqp = (const float*)d_in[11];
  const float* wkp = (const float*)d_in[12];
  const float* bkp = (const float*)d_in[13];
  const float* wo = (const float*)d_in[16];
  const float* bo = (const float*)d_in[17];
  const float* pscale = (const float*)d_in[18];
  float* out = (float*)d_out;

  char* cur = (char*)d_ws;
  const size_t NTOK = (size_t)BB * LL;  // 2048
  unsigned short* xh = (unsigned short*)cur; cur += NTOK * CCH * 2;
  unsigned short* xl = (unsigned short*)cur; cur += NTOK * CCH * 2;
  unsigned short* wt_h = (unsigned short*)cur; cur += (size_t)2240 * 512 * 2;
  unsigned short* qt = (unsigned short*)cur; cur += (size_t)16 * LL * 96 * 2;
  unsigned short* kt_ = (unsigned short*)cur; cur += (size_t)16 * LL * 96 * 2;
  unsigned short* vth = (unsigned short*)cur; cur += (size_t)16 * 64 * LL * 2;
  unsigned short* oh = (unsigned short*)cur; cur += NTOK * CCH * 2;
  float* po = (float*)cur; cur += (size_t)2 * 16 * LL * 64 * 4;
  float* pm = (float*)cur; cur += (size_t)2 * 16 * LL * 4;
  float* pl = (float*)cur; cur += (size_t)2 * 16 * LL * 4;

  // zero packed Q~/K~ (covers K=96 pad cols 76..95; qt,kt adjacent) and out
  hipMemsetAsync(qt, 0, (size_t)2 * 16 * LL * 96 * 2, stream);
  hipMemsetAsync(out, 0, NTOK * CCH * 4, stream);

  prep<<<dim3(2048 + 288), 256, 0, stream>>>(features, ln_g, ln_b, xh, xl, wq, wk,
                                             wv, wo, wqp, wkp, wt_h);
  proj_mfma<<<dim3(28, 32), 256, 0, stream>>>(xh, xl, wt_h, bq, bk, bv, bqp, bkp,
                                              pscale, qt, kt_, vth);
  ipa_attn_mfma<<<dim3(1024), 256, 0, stream>>>(qt, kt_, vth, po, pm, pl);
  merge_attn<<<dim3(4096), 256, 0, stream>>>(po, pm, pl, oh);
  out_proj_mfma<<<dim3(8, 32, 4), 256, 0, stream>>>(oh, wt_h, bo, out);
}

// Round 11
// 165.757 us; speedup vs baseline: 6.3979x; 1.1801x over previous
//
#include <hip/hip_runtime.h>
#include <math.h>

#define BB 2
#define LL 1024
#define CCH 512
#define HH 8
#define LN_EPSF 1e-5f

typedef short s16x8 __attribute__((ext_vector_type(8)));
typedef float fx4 __attribute__((ext_vector_type(4)));

// ---- fragment-contiguous layout ----
// All MFMA operand tensors are stored as 16(rows) x 32(k) tiles, each tile a
// contiguous 512-element block: element (r, k) at tile*512 + lane*8 + j where
// lane = ((k&31)>>3)*16 + (r&15), j = k&7. A wave's ldfrag is then ONE
// coalesced 1KB load (vs 16-way cache-line split in row-major).

__device__ __forceinline__ unsigned short f2bf(float f) {
  unsigned u = __float_as_uint(f);
  unsigned r = (u + 0x7FFFu + ((u >> 16) & 1u)) >> 16;
  return (unsigned short)r;
}
__device__ __forceinline__ float bf2f(unsigned short h) {
  return __uint_as_float(((unsigned)h) << 16);
}
__device__ __forceinline__ s16x8 ldfrag(const unsigned short* p) {
  int4 t = *(const int4*)p;
  return *(s16x8*)&t;
}

// ---- DPP row_ror reductions over 16-lane rows ----
template <int CTRL>
__device__ __forceinline__ float dpp_mov(float x) {
  return __int_as_float(
      __builtin_amdgcn_update_dpp(0, __float_as_int(x), CTRL, 0xF, 0xF, true));
}
__device__ __forceinline__ float red16_sum(float v) {
  v += dpp_mov<0x121>(v);
  v += dpp_mov<0x122>(v);
  v += dpp_mov<0x124>(v);
  v += dpp_mov<0x128>(v);
  return v;
}
__device__ __forceinline__ float red16_max(float v) {
  v = fmaxf(v, dpp_mov<0x121>(v));
  v = fmaxf(v, dpp_mov<0x122>(v));
  v = fmaxf(v, dpp_mov<0x124>(v));
  v = fmaxf(v, dpp_mov<0x128>(v));
  return v;
}
__device__ __forceinline__ float wave_sum(float v) {
  v = red16_sum(v);
  v += __shfl_xor(v, 16);
  v += __shfl_xor(v, 32);
  return v;
}

// ---------------- prep: LayerNorm (blocks 0..2047) + weight pack (2048..2335) ----------------
// ln: features -> split bf16 xh/xl, FRAGMENT layout [mt 128][kt 16].
// pack: W[k][n] fp32 -> wt_h FRAGMENT layout [nt][kt 16] (n-tile-major);
// n-tile bases: q:0, k:32, v:64, o:96, qp:128, kp:134.
__global__ __launch_bounds__(256) void prep(
    const float* __restrict__ f, const float* __restrict__ g,
    const float* __restrict__ bta, unsigned short* __restrict__ xh,
    unsigned short* __restrict__ xl, const float* __restrict__ wq,
    const float* __restrict__ wk, const float* __restrict__ wv,
    const float* __restrict__ wo, const float* __restrict__ wqp,
    const float* __restrict__ wkp, unsigned short* __restrict__ wt_h) {
  __shared__ unsigned short lh[64][68];
  __shared__ float red[8];
  const int tid = threadIdx.x;
  if (blockIdx.x < 2048) {  // ---- LayerNorm ----
    const int row = blockIdx.x;
    const int wave = tid >> 6, lane = tid & 63;
    const float* fr = f + (size_t)row * CCH;
    float2 v = *(const float2*)&fr[tid * 2];
    float s = wave_sum(v.x + v.y);
    if (lane == 0) red[wave] = s;
    __syncthreads();
    float mu = (red[0] + red[1] + red[2] + red[3]) * (1.0f / CCH);
    float dx = v.x - mu, dy = v.y - mu;
    float sq = wave_sum(dx * dx + dy * dy);
    if (lane == 0) red[4 + wave] = sq;
    __syncthreads();
    float var = (red[4] + red[5] + red[6] + red[7]) * (1.0f / CCH);
    float inv = 1.0f / sqrtf(var + LN_EPSF);
    float2 gg = *(const float2*)&g[tid * 2];
    float2 bb = *(const float2*)&bta[tid * 2];
    float ox = dx * inv * gg.x + bb.x;
    float oy = dy * inv * gg.y + bb.y;
    unsigned short h0 = f2bf(ox), h1 = f2bf(oy);
    ushort2 hv; hv.x = h0; hv.y = h1;
    ushort2 lv; lv.x = f2bf(ox - bf2f(h0)); lv.y = f2bf(oy - bf2f(h1));
    const int k0c = tid * 2;  // even
    size_t addr = ((size_t)((row >> 4) * 16 + (k0c >> 5))) * 512 +
                  (((k0c >> 3) & 3) * 16 + (row & 15)) * 8 + (k0c & 7);
    *(ushort2*)&xh[addr] = hv;
    *(ushort2*)&xl[addr] = lv;
  } else {  // ---- weight pack ----
    const int bx = blockIdx.x - 2048;
    const float* W;
    int Ncols, rowbase, kt, nt;
    if (bx < 256) {
      int mat = bx >> 6, t = bx & 63;
      kt = t >> 3; nt = t & 7; Ncols = 512;
      if (mat == 0) { W = wq; rowbase = 0; }
      else if (mat == 1) { W = wk; rowbase = 512; }
      else if (mat == 2) { W = wv; rowbase = 1024; }
      else { W = wo; rowbase = 1536; }
    } else {
      int r = bx - 256; int mat = r >> 4; int t = r & 15;
      kt = t >> 1; nt = t & 1; Ncols = 96;
      if (mat == 0) { W = wqp; rowbase = 2048; }
      else { W = wkp; rowbase = 2144; }
    }
    const int k0 = kt * 64, n0 = nt * 64;
    const int c = tid & 63;
#pragma unroll
    for (int ii = 0; ii < 16; ++ii) {
      int r = ii * 4 + (tid >> 6);  // k-local
      float val = (n0 + c < Ncols) ? W[(size_t)(k0 + r) * Ncols + n0 + c] : 0.f;
      lh[r][c] = f2bf(val);
    }
    __syncthreads();
    const int base_nt = (rowbase >> 4) + (n0 >> 4);
    const int base_kt = (k0 >> 5);
#pragma unroll
    for (int cc = 0; cc < 2; ++cc) {
      int ch = cc * 256 + tid;
      int lane2 = ch & 63, ktl = (ch >> 6) & 1, ntl = ch >> 7;
      int l16c = lane2 & 15, quadc = lane2 >> 4;
      if (n0 + ntl * 16 < Ncols) {
        unsigned short th[8] __attribute__((aligned(16)));
#pragma unroll
        for (int jj = 0; jj < 8; ++jj)
          th[jj] = lh[ktl * 32 + quadc * 8 + jj][ntl * 16 + l16c];
        *(int4*)&wt_h[((size_t)((base_nt + ntl) * 16 + base_kt + ktl)) * 512 +
                      lane2 * 8] = *(int4*)th;
      }
    }
  }
}

// ---------------- MFMA core, fragment layout ----------------
// A tiles at (mt0+i)*16 + ks; B tiles at (ntbase + min(nt0+j, ntmax))*16 + ks.
template <int MF, int NF, int TERMS>
__device__ __forceinline__ void mfma_core_frag(
    const unsigned short* __restrict__ Ah, const unsigned short* __restrict__ Al,
    const unsigned short* __restrict__ Bt, int mt0, int ntbase, int nt0,
    int ntmax, int ks0, int ks1, fx4 acc[MF][NF]) {
  const int lane = threadIdx.x & 63;
  int bt[NF];
#pragma unroll
  for (int j = 0; j < NF; ++j) {
    int nt = nt0 + j;
    if (nt > ntmax) nt = ntmax;
    bt[j] = ntbase + nt;
  }
#pragma unroll
  for (int i = 0; i < MF; ++i)
#pragma unroll
    for (int j = 0; j < NF; ++j) acc[i][j] = (fx4){0.f, 0.f, 0.f, 0.f};
  for (int ks = ks0; ks < ks1; ++ks) {
    s16x8 ah[MF], al[MF], b[NF];
#pragma unroll
    for (int i = 0; i < MF; ++i) {
      size_t off = ((size_t)((mt0 + i) * 16 + ks)) * 512 + lane * 8;
      ah[i] = ldfrag(&Ah[off]);
      if (TERMS == 2) al[i] = ldfrag(&Al[off]);
    }
#pragma unroll
    for (int j = 0; j < NF; ++j)
      b[j] = ldfrag(&Bt[((size_t)(bt[j] * 16 + ks)) * 512 + lane * 8]);
#pragma unroll
    for (int i = 0; i < MF; ++i)
#pragma unroll
      for (int j = 0; j < NF; ++j) {
        acc[i][j] = __builtin_amdgcn_mfma_f32_16x16x32_bf16(ah[i], b[j], acc[i][j], 0, 0, 0);
        if (TERMS == 2)
          acc[i][j] = __builtin_amdgcn_mfma_f32_16x16x32_bf16(al[i], b[j], acc[i][j], 0, 0, 0);
      }
  }
}

// ---------------- Fused projections, 64x64 blocks. grid (28, 32) ----------------
// bx 0..7: q -> qt frag-pack; 8..15: k -> kt; 16..23: v (head bx-16) -> vth
// frag layout via LDS; 24,25: qp; 26,27: kp.
// qt/kt frag tiles: [bh][ltile 64][s 0..2]; vth: [bh][dtile 4][jtile 32].
__global__ __launch_bounds__(256, 4) void proj_mfma(
    const unsigned short* __restrict__ xh, const unsigned short* __restrict__ xl,
    const unsigned short* __restrict__ wt_h,
    const float* __restrict__ bq, const float* __restrict__ bk,
    const float* __restrict__ bv, const float* __restrict__ bqp,
    const float* __restrict__ bkp, const float* __restrict__ pscale,
    unsigned short* __restrict__ qt, unsigned short* __restrict__ kt_,
    unsigned short* __restrict__ vth) {
  __shared__ unsigned short vt_lds[64][72];
  const int bx = blockIdx.x;
  const int m0 = blockIdx.y * 64;
  const int tid = threadIdx.x;
  const int wave = __builtin_amdgcn_readfirstlane(tid >> 6);
  const int lane = tid & 63;
  const int quad = lane >> 4, l16 = lane & 15;
  const int mw = m0 + (wave & 1) * 32;
  const int mt0 = mw >> 4;

  if (bx < 16) {  // q or k scalar: hi-only
    const bool isq = bx < 8;
    const float* bias = isq ? bq : bk;
    unsigned short* pdst = isq ? qt : kt_;
    const int n0 = (bx & 7) * 64;
    const int nw = n0 + (wave >> 1) * 32;
    fx4 acc[2][2];
    mfma_core_frag<2, 2, 1>(xh, xh, wt_h, mt0, isq ? 0 : 32, nw >> 4, 31, 0, 16, acc);
#pragma unroll
    for (int j = 0; j < 2; ++j) {
      int n = nw + j * 16 + l16;
      int h = n >> 6, d = n & 63;
      float bb = bias[n];
#pragma unroll
      for (int i = 0; i < 2; ++i)
#pragma unroll
        for (int reg = 0; reg < 4; ++reg) {
          int row = mw + i * 16 + quad * 4 + reg;
          int bi = row >> 10, l = row & 1023;
          int bh2 = bi * 8 + h;
          float val = (acc[i][j][reg] + bb) * 0.35355339059f;  // 1/sqrt(8)
          size_t tile = ((size_t)(bh2 * 64 + (l >> 4))) * 3 + (d >> 5);
          pdst[tile * 512 + (((d >> 3) & 3) * 16 + (l & 15)) * 8 + (d & 7)] = f2bf(val);
        }
    }
  } else if (bx < 24) {  // v: split-A, one head per block -> vth frag via LDS
    const int h = bx - 16;
    const int nw = h * 64 + (wave >> 1) * 32;
    fx4 acc[2][2];
    mfma_core_frag<2, 2, 2>(xh, xl, wt_h, mt0, 64, nw >> 4, 31, 0, 16, acc);
#pragma unroll
    for (int j = 0; j < 2; ++j) {
      int dl = (wave >> 1) * 32 + j * 16 + l16;  // local d 0..63
      float bb = bv[h * 64 + dl];
#pragma unroll
      for (int i = 0; i < 2; ++i)
#pragma unroll
        for (int reg = 0; reg < 4; ++reg) {
          int lm = (wave & 1) * 32 + i * 16 + quad * 4 + reg;  // local row 0..63
          vt_lds[lm][dl] = f2bf(acc[i][j][reg] + bb);
        }
    }
    __syncthreads();
    const int b = m0 >> 10, l0 = m0 & 1023;
    const int bh2 = b * 8 + h;
#pragma unroll
    for (int cc = 0; cc < 2; ++cc) {
      int ch = cc * 256 + tid;
      int lane2 = ch & 63, jt = (ch >> 6) & 1, ft = ch >> 7;
      int l16c = lane2 & 15, quadc = lane2 >> 4;
      unsigned short th[8] __attribute__((aligned(16)));
#pragma unroll
      for (int jj = 0; jj < 8; ++jj)
        th[jj] = vt_lds[jt * 32 + quadc * 8 + jj][ft * 16 + l16c];
      size_t tile = ((size_t)(bh2 * 4 + ft)) * 32 + (l0 >> 5) + jt;
      *(int4*)&vth[tile * 512 + lane2 * 8] = *(int4*)th;
    }
  } else {  // qp / kp point: hi-only, 96 cols -> s=2 tile
    const bool isq = bx < 26;
    const float* bias = isq ? bqp : bkp;
    unsigned short* pdst = isq ? qt : kt_;
    const int n0 = (bx & 1) * 64;
    const int nw = n0 + (wave >> 1) * 32;
    fx4 acc[2][2];
    mfma_core_frag<2, 2, 1>(xh, xh, wt_h, mt0, isq ? 128 : 134, nw >> 4, 5, 0, 16, acc);
#pragma unroll
    for (int j = 0; j < 2; ++j) {
      int n = nw + j * 16 + l16;
      bool ok = n < 96;
      int nn = ok ? n : 0;
      int h = nn / 12, c = nn - h * 12;
      float sc = sqrtf(2.f * pscale[h]);
      float bb = bias[nn];
#pragma unroll
      for (int i = 0; i < 2; ++i)
#pragma unroll
        for (int reg = 0; reg < 4; ++reg) {
          int row = mw + i * 16 + quad * 4 + reg;
          int bi = row >> 10, l = row & 1023;
          int bh2 = bi * 8 + h;
          float val = (acc[i][j][reg] + bb) * sc;
          if (ok) {
            int kc = 64 + c;
            size_t tile = ((size_t)(bh2 * 64 + (l >> 4))) * 3 + 2;
            pdst[tile * 512 + (((kc >> 3) & 3) * 16 + (l & 15)) * 8 + (kc & 7)] =
                f2bf(val);
          }
        }
    }
  }
}

// ---------------- Output projection: hi-only A, K-split x4, atomic accumulate ----------------
// grid (8, 32, 4). oh frag layout [mt 128][kt 16]; wo at n-tile base 96.
__global__ __launch_bounds__(256, 4) void out_proj_mfma(
    const unsigned short* __restrict__ oh,
    const unsigned short* __restrict__ wt_h, const float* __restrict__ bo,
    float* __restrict__ out) {
  const int tid = threadIdx.x;
  const int wave = __builtin_amdgcn_readfirstlane(tid >> 6);
  const int lane = tid & 63;
  const int quad = lane >> 4, l16 = lane & 15;
  const int mw = blockIdx.y * 64 + (wave & 1) * 32;
  const int nw = blockIdx.x * 64 + (wave >> 1) * 32;
  const int kz = blockIdx.z;
  fx4 acc[2][2];
  mfma_core_frag<2, 2, 1>(oh, oh, wt_h, mw >> 4, 96, nw >> 4, 31, kz * 4,
                          kz * 4 + 4, acc);
#pragma unroll
  for (int j = 0; j < 2; ++j) {
    int n = nw + j * 16 + l16;
    float bb = (kz == 0) ? bo[n] : 0.f;
#pragma unroll
    for (int i = 0; i < 2; ++i)
#pragma unroll
      for (int reg = 0; reg < 4; ++reg) {
        int row = mw + i * 16 + quad * 4 + reg;
        atomicAdd(&out[(size_t)row * 512 + n], acc[i][j][reg] + bb);
      }
  }
}

// ---------------- Flash IPA attention, K-split x2, XCD-swizzled 1D grid ----------------
// 1024 blocks; bid%8 keeps a head-pair per XCD. Fragment-layout operand loads:
// every ldfrag is one coalesced 1KB wave load.
__global__ __launch_bounds__(256, 4) void ipa_attn_mfma(
    const unsigned short* __restrict__ qt, const unsigned short* __restrict__ kt_,
    const unsigned short* __restrict__ vth,
    float* __restrict__ po, float* __restrict__ pm, float* __restrict__ pl) {
  const int bid = blockIdx.x;
  const int low3 = bid & 7;
  const int slot = bid >> 3;
  const int qtile = slot & 31;
  const int t = slot >> 5;  // 0..3
  const int ksz = t & 1;
  const int bh = ((t >> 1) << 3) | low3;
  const int tid = threadIdx.x;
  const int wave = tid >> 6, lane = tid & 63;
  const int quad = lane >> 4, l16 = lane & 15;
  const int mstrip = wave & 1, khalf = wave >> 1;
  const int ibase = qtile * 32 + mstrip * 16;

  __shared__ unsigned short pb[4][16][32];
  __shared__ float obuf[4][16][64];
  __shared__ float mred[4][16], lred[4][16];
  __shared__ float qsl[4][16];

  s16x8 aq[3];
#pragma unroll
  for (int s = 0; s < 3; ++s)
    aq[s] = ldfrag(&qt[(((size_t)(bh * 64 + (ibase >> 4))) * 3 + s) * 512 + lane * 8]);

  // qsq for row ibase+l16: 0.5 * sum over point-slot (s=2) squares
  {
    float qp = 0.f;
#pragma unroll
    for (int j = 0; j < 8; ++j) {
      float v = bf2f((unsigned short)aq[2][j]);
      qp += v * v;
    }
    qp += __shfl_xor(qp, 16);
    qp += __shfl_xor(qp, 32);
    qsl[wave][l16] = 0.5f * qp;  // wave-private; in-wave DS ordering
  }
  float qs_r[4];
#pragma unroll
  for (int reg = 0; reg < 4; ++reg) qs_r[reg] = qsl[wave][quad * 4 + reg];

  fx4 o[4];
#pragma unroll
  for (int f = 0; f < 4; ++f) o[f] = (fx4){0.f, 0.f, 0.f, 0.f};
  float m_r[4], l_r[4];
#pragma unroll
  for (int reg = 0; reg < 4; ++reg) { m_r[reg] = -INFINITY; l_r[reg] = 0.f; }

  for (int kt2 = ksz * 8; kt2 < ksz * 8 + 8; ++kt2) {
    const int j0 = kt2 * 64 + khalf * 32;
    s16x8 bk[2][3];
#pragma unroll
    for (int f = 0; f < 2; ++f)
#pragma unroll
      for (int s = 0; s < 3; ++s)
        bk[f][s] = ldfrag(
            &kt_[(((size_t)(bh * 64 + (j0 >> 4) + f)) * 3 + s) * 512 + lane * 8]);
    s16x8 bvh[4];
#pragma unroll
    for (int f = 0; f < 4; ++f)
      bvh[f] = ldfrag(
          &vth[(((size_t)(bh * 4 + f)) * 32 + (j0 >> 5)) * 512 + lane * 8]);

    // ksq for keys j0+l16 (f=0) and j0+16+l16 (f=1) from the s=2 fragments
    float kp0 = 0.f, kp1 = 0.f;
#pragma unroll
    for (int j = 0; j < 8; ++j) {
      float v0 = bf2f((unsigned short)bk[0][2][j]);
      float v1 = bf2f((unsigned short)bk[1][2][j]);
      kp0 += v0 * v0;
      kp1 += v1 * v1;
    }
    kp0 += __shfl_xor(kp0, 16);
    kp0 += __shfl_xor(kp0, 32);
    kp1 += __shfl_xor(kp1, 16);
    kp1 += __shfl_xor(kp1, 32);
    float ks0 = 0.5f * kp0, ks1 = 0.5f * kp1;

    fx4 sa[2];
    sa[0] = (fx4){0.f, 0.f, 0.f, 0.f};
    sa[1] = (fx4){0.f, 0.f, 0.f, 0.f};
#pragma unroll
    for (int f = 0; f < 2; ++f)
#pragma unroll
      for (int s = 0; s < 3; ++s)
        sa[f] = __builtin_amdgcn_mfma_f32_16x16x32_bf16(aq[s], bk[f][s], sa[f], 0, 0, 0);

#pragma unroll
    for (int reg = 0; reg < 4; ++reg) {
      float z0 = sa[0][reg] - qs_r[reg] - ks0;
      float z1 = sa[1][reg] - qs_r[reg] - ks1;
      float mx = red16_max(fmaxf(z0, z1));
      float mnew = fmaxf(m_r[reg], mx);
      float p0 = __expf(z0 - mnew), p1 = __expf(z1 - mnew);
      float alpha = __expf(m_r[reg] - mnew);
      float psum = red16_sum(p0 + p1);
      l_r[reg] = l_r[reg] * alpha + psum;
      m_r[reg] = mnew;
      o[0][reg] *= alpha; o[1][reg] *= alpha; o[2][reg] *= alpha; o[3][reg] *= alpha;
      pb[wave][quad * 4 + reg][l16] = f2bf(p0);
      pb[wave][quad * 4 + reg][16 + l16] = f2bf(p1);
    }
    s16x8 ap = ldfrag(&pb[wave][l16][quad * 8]);
#pragma unroll
    for (int f = 0; f < 4; ++f)
      o[f] = __builtin_amdgcn_mfma_f32_16x16x32_bf16(ap, bvh[f], o[f], 0, 0, 0);
  }
  if (l16 == 0) {
#pragma unroll
    for (int reg = 0; reg < 4; ++reg) {
      mred[wave][quad * 4 + reg] = m_r[reg];
      lred[wave][quad * 4 + reg] = l_r[reg];
    }
  }
#pragma unroll
  for (int f = 0; f < 4; ++f)
#pragma unroll
    for (int reg = 0; reg < 4; ++reg)
      obuf[wave][quad * 4 + reg][f * 16 + l16] = o[f][reg];
  __syncthreads();
  if (khalf == 0) {
    const int pw = wave + 2;
    const size_t rbase = ((size_t)ksz * 16 + bh) * LL + ibase;
#pragma unroll
    for (int f = 0; f < 4; ++f)
#pragma unroll
      for (int reg = 0; reg < 4; ++reg) {
        int row = quad * 4 + reg;
        int d = f * 16 + l16;
        float m0v = mred[wave][row], m1v = mred[pw][row];
        float l0v = lred[wave][row], l1v = lred[pw][row];
        float M = fmaxf(m0v, m1v);
        float w0 = __expf(m0v - M), w1 = __expf(m1v - M);
        float Lv = l0v * w0 + l1v * w1;
        float val = obuf[wave][row][d] * w0 + obuf[pw][row][d] * w1;
        po[(rbase + row) * 64 + d] = val;
        if (f == 0 && l16 == 0) {
          pm[rbase + row] = M;
          pl[rbase + row] = Lv;
        }
      }
  }
}

// ---------------- Merge the 2 K-split partials -> oh (bf16, FRAGMENT layout) ----------------
__global__ __launch_bounds__(256) void merge_attn(const float* __restrict__ po,
                                                  const float* __restrict__ pm,
                                                  const float* __restrict__ pl,
                                                  unsigned short* __restrict__ oh) {
  const int r = blockIdx.x * 4 + (threadIdx.x >> 6);  // row in [0, 16*1024)
  const int lane = threadIdx.x & 63;
  const size_t part = (size_t)16 * LL;
  float m0 = pm[r], m1 = pm[part + r];
  float l0 = pl[r], l1 = pl[part + r];
  float M = fmaxf(m0, m1);
  float w0 = __expf(m0 - M), w1 = __expf(m1 - M);
  float L = l0 * w0 + l1 * w1;
  float v = (po[(size_t)r * 64 + lane] * w0 + po[(part + r) * 64 + lane] * w1) / L;
  int bh = r >> 10, l = r & 1023;
  int b = bh >> 3, h = bh & 7;
  int m = b * LL + l;           // token row
  int kcol = h * 64 + lane;     // column in [0,512)
  size_t tile = ((size_t)(m >> 4)) * 16 + (kcol >> 5);
  oh[tile * 512 + (((kcol >> 3) & 3) * 16 + (m & 15)) * 8 + (kcol & 7)] = f2bf(v);
}

extern "C" void kernel_launch(void* const* d_in, const int* in_sizes, int n_in,
                              void* d_out, int out_size, void* d_ws, size_t ws_size,
                              hipStream_t stream) {
  (void)in_sizes; (void)n_in; (void)out_size; (void)ws_size;
  const float* features = (const float*)d_in[0];
  const float* ln_g = (const float*)d_in[2];
  const float* ln_b = (const float*)d_in[3];
  const float* wq = (const float*)d_in[4];
  const float* bq = (const float*)d_in[5];
  const float* wk = (const float*)d_in[6];
  const float* bk = (const float*)d_in[7];
  const float* wv = (const float*)d_in[8];
  const float* bv = (const float*)d_in[9];
  const float* wqp = (const float*)d_in[10];
  const float* bqp = (const float*)d_in[11];
  const float* wkp = (const float*)d_in[12];
  const float* bkp = (const float*)d_in[13];
  const float* wo = (const float*)d_in[16];
  const float* bo = (const float*)d_in[17];
  const float* pscale = (const float*)d_in[18];
  float* out = (float*)d_out;

  char* cur = (char*)d_ws;
  const size_t NTOK = (size_t)BB * LL;  // 2048
  unsigned short* xh = (unsigned short*)cur; cur += NTOK * CCH * 2;
  unsigned short* xl = (unsigned short*)cur; cur += NTOK * CCH * 2;
  unsigned short* wt_h = (unsigned short*)cur; cur += (size_t)2240 * 512 * 2;
  unsigned short* qt = (unsigned short*)cur; cur += (size_t)16 * LL * 96 * 2;
  unsigned short* kt_ = (unsigned short*)cur; cur += (size_t)16 * LL * 96 * 2;
  unsigned short* vth = (unsigned short*)cur; cur += (size_t)16 * 64 * LL * 2;
  unsigned short* oh = (unsigned short*)cur; cur += NTOK * CCH * 2;
  float* po = (float*)cur; cur += (size_t)2 * 16 * LL * 64 * 4;
  float* pm = (float*)cur; cur += (size_t)2 * 16 * LL * 4;
  float* pl = (float*)cur; cur += (size_t)2 * 16 * LL * 4;

  // zero packed Q~/K~ (covers the s=2 tile pad cols 76..95; qt,kt adjacent)
  // and out (atomic accumulation target)
  hipMemsetAsync(qt, 0, (size_t)2 * 16 * LL * 96 * 2, stream);
  hipMemsetAsync(out, 0, NTOK * CCH * 4, stream);

  prep<<<dim3(2048 + 288), 256, 0, stream>>>(features, ln_g, ln_b, xh, xl, wq, wk,
                                             wv, wo, wqp, wkp, wt_h);
  proj_mfma<<<dim3(28, 32), 256, 0, stream>>>(xh, xl, wt_h, bq, bk, bv, bqp, bkp,
                                              pscale, qt, kt_, vth);
  ipa_attn_mfma<<<dim3(1024), 256, 0, stream>>>(qt, kt_, vth, po, pm, pl);
  merge_attn<<<dim3(4096), 256, 0, stream>>>(po, pm, pl, oh);
  out_proj_mfma<<<dim3(8, 32, 4), 256, 0, stream>>>(oh, wt_h, bo, out);
}

// Round 12
// 155.468 us; speedup vs baseline: 6.8214x; 1.0662x over previous
//
#include <hip/hip_runtime.h>
#include <math.h>

#define BB 2
#define LL 1024
#define CCH 512
#define HH 8
#define LN_EPSF 1e-5f

typedef short s16x8 __attribute__((ext_vector_type(8)));
typedef float fx4 __attribute__((ext_vector_type(4)));

// ---- fragment-contiguous layout ----
// All MFMA operand tensors are stored as 16(rows) x 32(k) tiles, each tile a
// contiguous 512-element block: element (r, k) at tile*512 + lane*8 + j where
// lane = ((k&31)>>3)*16 + (r&15), j = k&7. A wave's ldfrag is then ONE
// coalesced 1KB load (vs 16-way cache-line split in row-major).

__device__ __forceinline__ unsigned short f2bf(float f) {
  unsigned u = __float_as_uint(f);
  unsigned r = (u + 0x7FFFu + ((u >> 16) & 1u)) >> 16;
  return (unsigned short)r;
}
__device__ __forceinline__ float bf2f(unsigned short h) {
  return __uint_as_float(((unsigned)h) << 16);
}
__device__ __forceinline__ s16x8 ldfrag(const unsigned short* p) {
  int4 t = *(const int4*)p;
  return *(s16x8*)&t;
}

// ---- DPP row_ror reductions over 16-lane rows ----
template <int CTRL>
__device__ __forceinline__ float dpp_mov(float x) {
  return __int_as_float(
      __builtin_amdgcn_update_dpp(0, __float_as_int(x), CTRL, 0xF, 0xF, true));
}
__device__ __forceinline__ float red16_sum(float v) {
  v += dpp_mov<0x121>(v);
  v += dpp_mov<0x122>(v);
  v += dpp_mov<0x124>(v);
  v += dpp_mov<0x128>(v);
  return v;
}
__device__ __forceinline__ float red16_max(float v) {
  v = fmaxf(v, dpp_mov<0x121>(v));
  v = fmaxf(v, dpp_mov<0x122>(v));
  v = fmaxf(v, dpp_mov<0x124>(v));
  v = fmaxf(v, dpp_mov<0x128>(v));
  return v;
}
__device__ __forceinline__ float wave_sum(float v) {
  v = red16_sum(v);
  v += __shfl_xor(v, 16);
  v += __shfl_xor(v, 32);
  return v;
}

// ---------------- prep ----------------
// blocks 0..2047: LayerNorm -> split bf16 xh/xl, FRAGMENT layout.
// blocks 2048..2335: weight pack -> wt_h FRAGMENT layout
//   (n-tile bases: q:0, k:32, v:64, o:96, qp:128, kp:134).
// blocks 2336..2399: zero the s=2 tile tails of qt/kt (positions 128..512;
//   proj later overwrites the kc=72..75 sub-slots).
// blocks 2400..2655: zero `out` (atomic accumulation target for out_proj).
__global__ __launch_bounds__(256) void prep(
    const float* __restrict__ f, const float* __restrict__ g,
    const float* __restrict__ bta, unsigned short* __restrict__ xh,
    unsigned short* __restrict__ xl, const float* __restrict__ wq,
    const float* __restrict__ wk, const float* __restrict__ wv,
    const float* __restrict__ wo, const float* __restrict__ wqp,
    const float* __restrict__ wkp, unsigned short* __restrict__ wt_h,
    unsigned short* __restrict__ qt, unsigned short* __restrict__ kt_,
    float* __restrict__ out) {
  __shared__ unsigned short lh[64][68];
  __shared__ float red[8];
  const int tid = threadIdx.x;
  const int bxg = blockIdx.x;
  if (bxg < 2048) {  // ---- LayerNorm ----
    const int row = bxg;
    const int wave = tid >> 6, lane = tid & 63;
    const float* fr = f + (size_t)row * CCH;
    float2 v = *(const float2*)&fr[tid * 2];
    float s = wave_sum(v.x + v.y);
    if (lane == 0) red[wave] = s;
    __syncthreads();
    float mu = (red[0] + red[1] + red[2] + red[3]) * (1.0f / CCH);
    float dx = v.x - mu, dy = v.y - mu;
    float sq = wave_sum(dx * dx + dy * dy);
    if (lane == 0) red[4 + wave] = sq;
    __syncthreads();
    float var = (red[4] + red[5] + red[6] + red[7]) * (1.0f / CCH);
    float inv = 1.0f / sqrtf(var + LN_EPSF);
    float2 gg = *(const float2*)&g[tid * 2];
    float2 bb = *(const float2*)&bta[tid * 2];
    float ox = dx * inv * gg.x + bb.x;
    float oy = dy * inv * gg.y + bb.y;
    unsigned short h0 = f2bf(ox), h1 = f2bf(oy);
    ushort2 hv; hv.x = h0; hv.y = h1;
    ushort2 lv; lv.x = f2bf(ox - bf2f(h0)); lv.y = f2bf(oy - bf2f(h1));
    const int k0c = tid * 2;  // even
    size_t addr = ((size_t)((row >> 4) * 16 + (k0c >> 5))) * 512 +
                  (((k0c >> 3) & 3) * 16 + (row & 15)) * 8 + (k0c & 7);
    *(ushort2*)&xh[addr] = hv;
    *(ushort2*)&xl[addr] = lv;
  } else if (bxg < 2336) {  // ---- weight pack ----
    const int bx = bxg - 2048;
    const float* W;
    int Ncols, rowbase, kt, nt;
    if (bx < 256) {
      int mat = bx >> 6, t = bx & 63;
      kt = t >> 3; nt = t & 7; Ncols = 512;
      if (mat == 0) { W = wq; rowbase = 0; }
      else if (mat == 1) { W = wk; rowbase = 512; }
      else if (mat == 2) { W = wv; rowbase = 1024; }
      else { W = wo; rowbase = 1536; }
    } else {
      int r = bx - 256; int mat = r >> 4; int t = r & 15;
      kt = t >> 1; nt = t & 1; Ncols = 96;
      if (mat == 0) { W = wqp; rowbase = 2048; }
      else { W = wkp; rowbase = 2144; }
    }
    const int k0 = kt * 64, n0 = nt * 64;
    const int c = tid & 63;
#pragma unroll
    for (int ii = 0; ii < 16; ++ii) {
      int r = ii * 4 + (tid >> 6);  // k-local
      float val = (n0 + c < Ncols) ? W[(size_t)(k0 + r) * Ncols + n0 + c] : 0.f;
      lh[r][c] = f2bf(val);
    }
    __syncthreads();
    const int base_nt = (rowbase >> 4) + (n0 >> 4);
    const int base_kt = (k0 >> 5);
#pragma unroll
    for (int cc = 0; cc < 2; ++cc) {
      int ch = cc * 256 + tid;
      int lane2 = ch & 63, ktl = (ch >> 6) & 1, ntl = ch >> 7;
      int l16c = lane2 & 15, quadc = lane2 >> 4;
      if (n0 + ntl * 16 < Ncols) {
        unsigned short th[8] __attribute__((aligned(16)));
#pragma unroll
        for (int jj = 0; jj < 8; ++jj)
          th[jj] = lh[ktl * 32 + quadc * 8 + jj][ntl * 16 + l16c];
        *(int4*)&wt_h[((size_t)((base_nt + ntl) * 16 + base_kt + ktl)) * 512 +
                      lane2 * 8] = *(int4*)th;
      }
    }
  } else if (bxg < 2400) {  // ---- zero qt/kt s=2 tile tails ----
    const int vb2 = bxg - 2336;  // [0,64): 32 s=2 tiles each
    const int4 zero = {0, 0, 0, 0};
    for (int u = tid; u < 32 * 48; u += 256) {  // 48 int4 (8 shorts) per tile
      int t = u / 48, off = (u - t * 48) * 8;
      int gidx = vb2 * 32 + t;  // [0,2048)
      unsigned short* dst = (gidx < 1024) ? qt : kt_;
      int rem = gidx & 1023;
      int bh = rem >> 6, lt = rem & 63;
      size_t base = ((size_t)(bh * 64 + lt) * 3 + 2) * 512;
      *(int4*)&dst[base + 128 + off] = zero;
    }
  } else {  // ---- zero out ----
    const int vb3 = bxg - 2400;  // [0,256): 4096 floats each
    const float4 zero = {0.f, 0.f, 0.f, 0.f};
    float4* dst = (float4*)(out + (size_t)vb3 * 4096);
#pragma unroll
    for (int i = 0; i < 4; ++i) dst[i * 256 + tid] = zero;
  }
}

// ---------------- MFMA core, fragment layout ----------------
// A tiles at (mt0+i)*16 + ks; B tiles at (ntbase + min(nt0+j, ntmax))*16 + ks.
template <int MF, int NF, int TERMS>
__device__ __forceinline__ void mfma_core_frag(
    const unsigned short* __restrict__ Ah, const unsigned short* __restrict__ Al,
    const unsigned short* __restrict__ Bt, int mt0, int ntbase, int nt0,
    int ntmax, int ks0, int ks1, fx4 acc[MF][NF]) {
  const int lane = threadIdx.x & 63;
  int bt[NF];
#pragma unroll
  for (int j = 0; j < NF; ++j) {
    int nt = nt0 + j;
    if (nt > ntmax) nt = ntmax;
    bt[j] = ntbase + nt;
  }
#pragma unroll
  for (int i = 0; i < MF; ++i)
#pragma unroll
    for (int j = 0; j < NF; ++j) acc[i][j] = (fx4){0.f, 0.f, 0.f, 0.f};
  for (int ks = ks0; ks < ks1; ++ks) {
    s16x8 ah[MF], al[MF], b[NF];
#pragma unroll
    for (int i = 0; i < MF; ++i) {
      size_t off = ((size_t)((mt0 + i) * 16 + ks)) * 512 + lane * 8;
      ah[i] = ldfrag(&Ah[off]);
      if (TERMS == 2) al[i] = ldfrag(&Al[off]);
    }
#pragma unroll
    for (int j = 0; j < NF; ++j)
      b[j] = ldfrag(&Bt[((size_t)(bt[j] * 16 + ks)) * 512 + lane * 8]);
#pragma unroll
    for (int i = 0; i < MF; ++i)
#pragma unroll
      for (int j = 0; j < NF; ++j) {
        acc[i][j] = __builtin_amdgcn_mfma_f32_16x16x32_bf16(ah[i], b[j], acc[i][j], 0, 0, 0);
        if (TERMS == 2)
          acc[i][j] = __builtin_amdgcn_mfma_f32_16x16x32_bf16(al[i], b[j], acc[i][j], 0, 0, 0);
      }
  }
}

// ---------------- Fused projections, 64x64 blocks. grid (28, 32) ----------------
// bx 0..7: q -> qt frag-pack; 8..15: k -> kt; 16..23: v (head bx-16) -> vth
// frag layout via LDS; 24,25: qp; 26,27: kp.
// qt/kt frag tiles: [bh][ltile 64][s 0..2]; vth: [bh][dtile 4][jtile 32].
__global__ __launch_bounds__(256, 4) void proj_mfma(
    const unsigned short* __restrict__ xh, const unsigned short* __restrict__ xl,
    const unsigned short* __restrict__ wt_h,
    const float* __restrict__ bq, const float* __restrict__ bk,
    const float* __restrict__ bv, const float* __restrict__ bqp,
    const float* __restrict__ bkp, const float* __restrict__ pscale,
    unsigned short* __restrict__ qt, unsigned short* __restrict__ kt_,
    unsigned short* __restrict__ vth) {
  __shared__ unsigned short vt_lds[64][72];
  const int bx = blockIdx.x;
  const int m0 = blockIdx.y * 64;
  const int tid = threadIdx.x;
  const int wave = __builtin_amdgcn_readfirstlane(tid >> 6);
  const int lane = tid & 63;
  const int quad = lane >> 4, l16 = lane & 15;
  const int mw = m0 + (wave & 1) * 32;
  const int mt0 = mw >> 4;

  if (bx < 16) {  // q or k scalar: hi-only
    const bool isq = bx < 8;
    const float* bias = isq ? bq : bk;
    unsigned short* pdst = isq ? qt : kt_;
    const int n0 = (bx & 7) * 64;
    const int nw = n0 + (wave >> 1) * 32;
    fx4 acc[2][2];
    mfma_core_frag<2, 2, 1>(xh, xh, wt_h, mt0, isq ? 0 : 32, nw >> 4, 31, 0, 16, acc);
#pragma unroll
    for (int j = 0; j < 2; ++j) {
      int n = nw + j * 16 + l16;
      int h = n >> 6, d = n & 63;
      float bb = bias[n];
#pragma unroll
      for (int i = 0; i < 2; ++i)
#pragma unroll
        for (int reg = 0; reg < 4; ++reg) {
          int row = mw + i * 16 + quad * 4 + reg;
          int bi = row >> 10, l = row & 1023;
          int bh2 = bi * 8 + h;
          float val = (acc[i][j][reg] + bb) * 0.35355339059f;  // 1/sqrt(8)
          size_t tile = ((size_t)(bh2 * 64 + (l >> 4))) * 3 + (d >> 5);
          pdst[tile * 512 + (((d >> 3) & 3) * 16 + (l & 15)) * 8 + (d & 7)] = f2bf(val);
        }
    }
  } else if (bx < 24) {  // v: split-A, one head per block -> vth frag via LDS
    const int h = bx - 16;
    const int nw = h * 64 + (wave >> 1) * 32;
    fx4 acc[2][2];
    mfma_core_frag<2, 2, 2>(xh, xl, wt_h, mt0, 64, nw >> 4, 31, 0, 16, acc);
#pragma unroll
    for (int j = 0; j < 2; ++j) {
      int dl = (wave >> 1) * 32 + j * 16 + l16;  // local d 0..63
      float bb = bv[h * 64 + dl];
#pragma unroll
      for (int i = 0; i < 2; ++i)
#pragma unroll
        for (int reg = 0; reg < 4; ++reg) {
          int lm = (wave & 1) * 32 + i * 16 + quad * 4 + reg;  // local row 0..63
          vt_lds[lm][dl] = f2bf(acc[i][j][reg] + bb);
        }
    }
    __syncthreads();
    const int b = m0 >> 10, l0 = m0 & 1023;
    const int bh2 = b * 8 + h;
#pragma unroll
    for (int cc = 0; cc < 2; ++cc) {
      int ch = cc * 256 + tid;
      int lane2 = ch & 63, jt = (ch >> 6) & 1, ft = ch >> 7;
      int l16c = lane2 & 15, quadc = lane2 >> 4;
      unsigned short th[8] __attribute__((aligned(16)));
#pragma unroll
      for (int jj = 0; jj < 8; ++jj)
        th[jj] = vt_lds[jt * 32 + quadc * 8 + jj][ft * 16 + l16c];
      size_t tile = ((size_t)(bh2 * 4 + ft)) * 32 + (l0 >> 5) + jt;
      *(int4*)&vth[tile * 512 + lane2 * 8] = *(int4*)th;
    }
  } else {  // qp / kp point: hi-only, 96 cols -> s=2 tile
    const bool isq = bx < 26;
    const float* bias = isq ? bqp : bkp;
    unsigned short* pdst = isq ? qt : kt_;
    const int n0 = (bx & 1) * 64;
    const int nw = n0 + (wave >> 1) * 32;
    fx4 acc[2][2];
    mfma_core_frag<2, 2, 1>(xh, xh, wt_h, mt0, isq ? 128 : 134, nw >> 4, 5, 0, 16, acc);
#pragma unroll
    for (int j = 0; j < 2; ++j) {
      int n = nw + j * 16 + l16;
      bool ok = n < 96;
      int nn = ok ? n : 0;
      int h = nn / 12, c = nn - h * 12;
      float sc = sqrtf(2.f * pscale[h]);
      float bb = bias[nn];
#pragma unroll
      for (int i = 0; i < 2; ++i)
#pragma unroll
        for (int reg = 0; reg < 4; ++reg) {
          int row = mw + i * 16 + quad * 4 + reg;
          int bi = row >> 10, l = row & 1023;
          int bh2 = bi * 8 + h;
          float val = (acc[i][j][reg] + bb) * sc;
          if (ok) {
            int kc = 64 + c;
            size_t tile = ((size_t)(bh2 * 64 + (l >> 4))) * 3 + 2;
            pdst[tile * 512 + (((kc >> 3) & 3) * 16 + (l & 15)) * 8 + (kc & 7)] =
                f2bf(val);
          }
        }
    }
  }
}

// ---------------- Output projection: hi-only A, K-split x4, atomic accumulate ----------------
// grid (8, 32, 4). oh frag layout [mt 128][kt 16]; wo at n-tile base 96.
// out pre-zeroed by prep.
__global__ __launch_bounds__(256, 4) void out_proj_mfma(
    const unsigned short* __restrict__ oh,
    const unsigned short* __restrict__ wt_h, const float* __restrict__ bo,
    float* __restrict__ out) {
  const int tid = threadIdx.x;
  const int wave = __builtin_amdgcn_readfirstlane(tid >> 6);
  const int lane = tid & 63;
  const int quad = lane >> 4, l16 = lane & 15;
  const int mw = blockIdx.y * 64 + (wave & 1) * 32;
  const int nw = blockIdx.x * 64 + (wave >> 1) * 32;
  const int kz = blockIdx.z;
  fx4 acc[2][2];
  mfma_core_frag<2, 2, 1>(oh, oh, wt_h, mw >> 4, 96, nw >> 4, 31, kz * 4,
                          kz * 4 + 4, acc);
#pragma unroll
  for (int j = 0; j < 2; ++j) {
    int n = nw + j * 16 + l16;
    float bb = (kz == 0) ? bo[n] : 0.f;
#pragma unroll
    for (int i = 0; i < 2; ++i)
#pragma unroll
      for (int reg = 0; reg < 4; ++reg) {
        int row = mw + i * 16 + quad * 4 + reg;
        atomicAdd(&out[(size_t)row * 512 + n], acc[i][j][reg] + bb);
      }
  }
}

// ---------------- Flash IPA attention: in-block K-split, 512 threads ----------------
// 512 blocks (bid%8 keeps a head-pair per XCD); 8 waves = 2 mstrips x 4
// K-quarters. Each wave: 8 iters of 32 keys over its quarter. Final 4-way
// flash merge across K-quarter waves via LDS; writes oh directly (fragment
// layout). No partial buffers, no merge kernel.
__global__ __launch_bounds__(512, 4) void ipa_attn_mfma(
    const unsigned short* __restrict__ qt, const unsigned short* __restrict__ kt_,
    const unsigned short* __restrict__ vth, unsigned short* __restrict__ oh) {
  const int bid = blockIdx.x;
  const int low3 = bid & 7;
  const int slot = bid >> 3;  // [0,64)
  const int qtile = slot & 31;
  const int bh = ((slot >> 5) << 3) | low3;
  const int tid = threadIdx.x;
  const int wave = tid >> 6, lane = tid & 63;
  const int quad = lane >> 4, l16 = lane & 15;
  const int mstrip = wave & 1, kq = wave >> 1;  // kq in [0,4)
  const int ibase = qtile * 32 + mstrip * 16;

  __shared__ unsigned short pb[8][16][32];
  __shared__ float obuf[8][16][64];
  __shared__ float mred[8][16], lred[8][16];
  __shared__ float qsl[8][16];

  s16x8 aq[3];
#pragma unroll
  for (int s = 0; s < 3; ++s)
    aq[s] = ldfrag(&qt[(((size_t)(bh * 64 + (ibase >> 4))) * 3 + s) * 512 + lane * 8]);

  // qsq for row ibase+l16: 0.5 * sum over point-slot (s=2) squares
  {
    float qp = 0.f;
#pragma unroll
    for (int j = 0; j < 8; ++j) {
      float v = bf2f((unsigned short)aq[2][j]);
      qp += v * v;
    }
    qp += __shfl_xor(qp, 16);
    qp += __shfl_xor(qp, 32);
    qsl[wave][l16] = 0.5f * qp;  // wave-private; in-wave DS ordering
  }
  float qs_r[4];
#pragma unroll
  for (int reg = 0; reg < 4; ++reg) qs_r[reg] = qsl[wave][quad * 4 + reg];

  fx4 o[4];
#pragma unroll
  for (int f = 0; f < 4; ++f) o[f] = (fx4){0.f, 0.f, 0.f, 0.f};
  float m_r[4], l_r[4];
#pragma unroll
  for (int reg = 0; reg < 4; ++reg) { m_r[reg] = -INFINITY; l_r[reg] = 0.f; }

#pragma unroll 1
  for (int c = 0; c < 8; ++c) {
    const int j0 = kq * 256 + c * 32;
    s16x8 bk[2][3];
#pragma unroll
    for (int f = 0; f < 2; ++f)
#pragma unroll
      for (int s = 0; s < 3; ++s)
        bk[f][s] = ldfrag(
            &kt_[(((size_t)(bh * 64 + (j0 >> 4) + f)) * 3 + s) * 512 + lane * 8]);
    s16x8 bvh[4];
#pragma unroll
    for (int f = 0; f < 4; ++f)
      bvh[f] = ldfrag(
          &vth[(((size_t)(bh * 4 + f)) * 32 + (j0 >> 5)) * 512 + lane * 8]);

    // ksq for keys j0+l16 (f=0) and j0+16+l16 (f=1) from the s=2 fragments
    float kp0 = 0.f, kp1 = 0.f;
#pragma unroll
    for (int j = 0; j < 8; ++j) {
      float v0 = bf2f((unsigned short)bk[0][2][j]);
      float v1 = bf2f((unsigned short)bk[1][2][j]);
      kp0 += v0 * v0;
      kp1 += v1 * v1;
    }
    kp0 += __shfl_xor(kp0, 16);
    kp0 += __shfl_xor(kp0, 32);
    kp1 += __shfl_xor(kp1, 16);
    kp1 += __shfl_xor(kp1, 32);
    float ks0 = 0.5f * kp0, ks1 = 0.5f * kp1;

    fx4 sa[2];
    sa[0] = (fx4){0.f, 0.f, 0.f, 0.f};
    sa[1] = (fx4){0.f, 0.f, 0.f, 0.f};
#pragma unroll
    for (int f = 0; f < 2; ++f)
#pragma unroll
      for (int s = 0; s < 3; ++s)
        sa[f] = __builtin_amdgcn_mfma_f32_16x16x32_bf16(aq[s], bk[f][s], sa[f], 0, 0, 0);

#pragma unroll
    for (int reg = 0; reg < 4; ++reg) {
      float z0 = sa[0][reg] - qs_r[reg] - ks0;
      float z1 = sa[1][reg] - qs_r[reg] - ks1;
      float mx = red16_max(fmaxf(z0, z1));
      float mnew = fmaxf(m_r[reg], mx);
      float p0 = __expf(z0 - mnew), p1 = __expf(z1 - mnew);
      float alpha = __expf(m_r[reg] - mnew);
      float psum = red16_sum(p0 + p1);
      l_r[reg] = l_r[reg] * alpha + psum;
      m_r[reg] = mnew;
      o[0][reg] *= alpha; o[1][reg] *= alpha; o[2][reg] *= alpha; o[3][reg] *= alpha;
      pb[wave][quad * 4 + reg][l16] = f2bf(p0);
      pb[wave][quad * 4 + reg][16 + l16] = f2bf(p1);
    }
    s16x8 ap = ldfrag(&pb[wave][l16][quad * 8]);
#pragma unroll
    for (int f = 0; f < 4; ++f)
      o[f] = __builtin_amdgcn_mfma_f32_16x16x32_bf16(ap, bvh[f], o[f], 0, 0, 0);
  }
  if (l16 == 0) {
#pragma unroll
    for (int reg = 0; reg < 4; ++reg) {
      mred[wave][quad * 4 + reg] = m_r[reg];
      lred[wave][quad * 4 + reg] = l_r[reg];
    }
  }
#pragma unroll
  for (int f = 0; f < 4; ++f)
#pragma unroll
    for (int reg = 0; reg < 4; ++reg)
      obuf[wave][quad * 4 + reg][f * 16 + l16] = o[f][reg];
  __syncthreads();
  if (kq == 0) {  // waves 0,1 merge the 4 K-quarter partials of their mstrip
    const int b = bh >> 3, h = bh & 7;
#pragma unroll
    for (int f = 0; f < 4; ++f)
#pragma unroll
      for (int reg = 0; reg < 4; ++reg) {
        int row = quad * 4 + reg;
        int d = f * 16 + l16;
        float M = -INFINITY;
#pragma unroll
        for (int p = 0; p < 4; ++p) M = fmaxf(M, mred[wave + p * 2][row]);
        float L = 0.f, val = 0.f;
#pragma unroll
        for (int p = 0; p < 4; ++p) {
          float w = __expf(mred[wave + p * 2][row] - M);
          L += lred[wave + p * 2][row] * w;
          val += obuf[wave + p * 2][row][d] * w;
        }
        val /= L;
        int m = b * LL + ibase + row;     // token row
        int kcol = h * 64 + d;            // column in [0,512)
        size_t tile = ((size_t)(m >> 4)) * 16 + (kcol >> 5);
        oh[tile * 512 + (((kcol >> 3) & 3) * 16 + (m & 15)) * 8 + (kcol & 7)] =
            f2bf(val);
      }
  }
}

extern "C" void kernel_launch(void* const* d_in, const int* in_sizes, int n_in,
                              void* d_out, int out_size, void* d_ws, size_t ws_size,
                              hipStream_t stream) {
  (void)in_sizes; (void)n_in; (void)out_size; (void)ws_size;
  const float* features = (const float*)d_in[0];
  const float* ln_g = (const float*)d_in[2];
  const float* ln_b = (const float*)d_in[3];
  const float* wq = (const float*)d_in[4];
  const float* bq = (const float*)d_in[5];
  const float* wk = (const float*)d_in[6];
  const float* bk = (const float*)d_in[7];
  const float* wv = (const float*)d_in[8];
  const float* bv = (const float*)d_in[9];
  const float* wqp = (const float*)d_in[10];
  const float* bqp = (const float*)d_in[11];
  const float* wkp = (const float*)d_in[12];
  const float* bkp = (const float*)d_in[13];
  const float* wo = (const float*)d_in[16];
  const float* bo = (const float*)d_in[17];
  const float* pscale = (const float*)d_in[18];
  float* out = (float*)d_out;

  char* cur = (char*)d_ws;
  const size_t NTOK = (size_t)BB * LL;  // 2048
  unsigned short* xh = (unsigned short*)cur; cur += NTOK * CCH * 2;
  unsigned short* xl = (unsigned short*)cur; cur += NTOK * CCH * 2;
  unsigned short* wt_h = (unsigned short*)cur; cur += (size_t)2240 * 512 * 2;
  unsigned short* qt = (unsigned short*)cur; cur += (size_t)16 * LL * 96 * 2;
  unsigned short* kt_ = (unsigned short*)cur; cur += (size_t)16 * LL * 96 * 2;
  unsigned short* vth = (unsigned short*)cur; cur += (size_t)16 * 64 * LL * 2;
  unsigned short* oh = (unsigned short*)cur; cur += NTOK * CCH * 2;

  prep<<<dim3(2656), 256, 0, stream>>>(features, ln_g, ln_b, xh, xl, wq, wk, wv,
                                       wo, wqp, wkp, wt_h, qt, kt_, out);
  proj_mfma<<<dim3(28, 32), 256, 0, stream>>>(xh, xl, wt_h, bq, bk, bv, bqp, bkp,
                                              pscale, qt, kt_, vth);
  ipa_attn_mfma<<<dim3(512), 512, 0, stream>>>(qt, kt_, vth, oh);
  out_proj_mfma<<<dim3(8, 32, 4), 256, 0, stream>>>(oh, wt_h, bo, out);
}